// Round 18
// baseline (589.893 us; speedup 1.0000x reference)
//
#include <hip/hip_runtime.h>

typedef __attribute__((ext_vector_type(8))) short bf16x8;
typedef __attribute__((ext_vector_type(8))) unsigned short u16x8;
typedef __attribute__((ext_vector_type(4))) unsigned short u16x4;
typedef __attribute__((ext_vector_type(4))) float f32x4;
typedef __attribute__((ext_vector_type(2))) unsigned uint2v;

#define DEV static __device__ __forceinline__

DEV unsigned short f2bf(float f){
  unsigned u = __float_as_uint(f);
  u += 0x7fff + ((u>>16)&1);
  return (unsigned short)(u>>16);
}
DEV float bf2f(unsigned short b){ return __uint_as_float(((unsigned)b)<<16); }
DEV unsigned cvtpk(float lo, float hi){
  unsigned r;
  asm("v_cvt_pk_bf16_f32 %0, %1, %2" : "=v"(r) : "v"(lo), "v"(hi));
  return r;
}

DEV void gll16(const void* g, void* l){
  __builtin_amdgcn_global_load_lds((__attribute__((address_space(1))) unsigned*)(void*)g,
                                   (__attribute__((address_space(3))) unsigned*)l, 16, 0, 0);
}

// ---------------- cast fp32 -> bf16 (vectorized) ----------------
__global__ void k_cast(const float* __restrict__ x, unsigned short* __restrict__ y, int n4){
  int i = blockIdx.x*256 + threadIdx.x;
  if (i >= n4) return;
  f32x4 v = ((const f32x4*)x)[i];
  u16x4 o = { f2bf(v.x), f2bf(v.y), f2bf(v.z), f2bf(v.w) };
  ((u16x4*)y)[i] = o;
}

// ---------------- 2-segment input cast (fallback path) ----------------
__global__ void k_castX2(const float* __restrict__ s0, const float* __restrict__ s1,
                         unsigned short* __restrict__ y){
  unsigned i = blockIdx.x*256 + threadIdx.x;          // < 2359296
  const float* s = (i < 1572864u) ? s0 : s1;
  unsigned off = (i < 1572864u) ? i : i - 1572864u;
  f32x4 v = ((const f32x4*)s)[off];
  u16x4 o = { f2bf(v.x), f2bf(v.y), f2bf(v.z), f2bf(v.w) };
  ((u16x4*)y)[i] = o;
}

// ---------------- unified cast: 6 QKV weight segs -> Wb, then hs|ehs -> Xc ----------------
__global__ void k_castA6X(const float* __restrict__ s0, const float* __restrict__ s1,
                          const float* __restrict__ s2, const float* __restrict__ s3,
                          const float* __restrict__ s4, const float* __restrict__ s5,
                          const float* __restrict__ xh, const float* __restrict__ xe,
                          unsigned short* __restrict__ Wb, unsigned short* __restrict__ Xc){
  unsigned i = blockIdx.x*256 + threadIdx.x;          // < 6*2359296 + 2359296
  const float* s; unsigned off; unsigned short* dst; unsigned di;
  if (i < 14155776u){
    unsigned seg = i / 2359296u;                      // block-uniform
    off = i - seg*2359296u;
    s = seg==0?s0: seg==1?s1: seg==2?s2: seg==3?s3: seg==4?s4: s5;
    dst = Wb; di = i;
  } else {
    unsigned j = i - 14155776u;                       // < 2359296
    s = (j < 1572864u) ? xh : xe;
    off = (j < 1572864u) ? j : j - 1572864u;
    dst = Xc; di = j;
  }
  f32x4 v = ((const f32x4*)s)[off];
  u16x4 o = { f2bf(v.x), f2bf(v.y), f2bf(v.z), f2bf(v.w) };
  ((u16x4*)dst)[di] = o;
}

// ---------------- 2-segment weight cast (wo/wao) ----------------
__global__ void k_castW2(const float* __restrict__ s0, const float* __restrict__ s1,
                         unsigned short* __restrict__ y){
  unsigned i = blockIdx.x*256 + threadIdx.x;          // < 2*2359296
  unsigned seg = i / 2359296u;
  unsigned off = i - seg*2359296u;
  const float* s = seg==0?s0:s1;
  f32x4 v = ((const f32x4*)s)[off];
  u16x4 o = { f2bf(v.x), f2bf(v.y), f2bf(v.z), f2bf(v.w) };
  ((u16x4*)y)[i] = o;
}

// ================= 256x256 8-wave QKV GEMM (BK=64, depth-1 dbuf) =================
// Round-17 proven (passed, ~175-185 us vs 308 for 128sq).
__global__ __launch_bounds__(512) void k_gemmP256(
    const unsigned short* __restrict__ X,
    const unsigned short* __restrict__ Wimg, const unsigned short* __restrict__ Wenc,
    const float* __restrict__ b0, const float* __restrict__ b1, const float* __restrict__ b2,
    const float* __restrict__ b3, const float* __restrict__ b4, const float* __restrict__ b5,
    unsigned short* __restrict__ Y, int rows_img)
{
  __shared__ unsigned short LDS[2][32768];   // per buf: A[256][64] @0, B[256][64] @16384 (elems)
  const int t = threadIdx.x, w = t>>6, l = t&63;
  const int li = l&15, g = l>>4;
  const int wr = w>>2, wc = w&3;             // 2 (M) x 4 (N) wave grid
  const int bxr = blockIdx.x, by = blockIdx.y;
  const int R = bxr*256;
  const int sec = by/12;                     // Q/K/V section
  const int Cn = (by%12)*256;                // col base within section
  const bool img = (R < rows_img);           // block-uniform
  const unsigned short* Wbase = (img ? Wimg : Wenc) + (long)sec*9437184 + (long)Cn*3072;
  const float* bias = img ? ((sec==0)?b0:(sec==1)?b1:b2)
                          : ((sec==0)?b3:(sec==1)?b4:b5);

  f32x4 acc[8][4] = {};

  auto stageC = [&](int buf, int kt, int c){
    int row = (c&3)*64 + (t>>3);
    int sgrp = (t&7) ^ (row&7);
    const unsigned short* src = (c<4)
        ? X + (long)(R+row)*3072 + kt*64 + sgrp*8
        : Wbase + (long)row*3072 + kt*64 + sgrp*8;
    gll16(src, &LDS[buf][(c<4?0:16384) + (c&3)*4096 + t*8]);
  };

  #pragma unroll
  for (int c=0;c<8;c++) stageC(0, 0, c);     // prologue: tile 0

  for (int kt=0; kt<48; kt++){
    __syncthreads();                         // tile kt resident; buf[(kt+1)&1] free
    const int buf = kt&1;
    const unsigned short* Ab = &LDS[buf][0];
    const unsigned short* Bb = &LDS[buf][16384];

    bf16x8 Bf[4][2];
    #pragma unroll
    for (int fc=0;fc<4;fc++)
      #pragma unroll
      for (int kh=0;kh<2;kh++){
        int brow = wc*64 + fc*16 + li;
        int bgrp = ((kh<<2) + g) ^ (brow&7);
        Bf[fc][kh] = *(const bf16x8*)&Bb[brow*64 + bgrp*8];
      }
    if (kt+1 < 48){
      #pragma unroll
      for (int c=0;c<4;c++) stageC(buf^1, kt+1, c);
    }

    #pragma unroll
    for (int p=0;p<4;p++){
      bf16x8 Af[2][2];
      #pragma unroll
      for (int f2=0;f2<2;f2++)
        #pragma unroll
        for (int kh=0;kh<2;kh++){
          int arow = wr*128 + (2*p+f2)*16 + li;
          int agrp = ((kh<<2) + g) ^ (arow&7);
          Af[f2][kh] = *(const bf16x8*)&Ab[arow*64 + agrp*8];
        }
      if (p==0 && kt+1 < 48){
        #pragma unroll
        for (int c=4;c<8;c++) stageC(buf^1, kt+1, c);
      }
      __builtin_amdgcn_s_setprio(1);
      #pragma unroll
      for (int f2=0;f2<2;f2++)
        #pragma unroll
        for (int fc=0;fc<4;fc++)
          #pragma unroll
          for (int kh=0;kh<2;kh++)
            acc[2*p+f2][fc] = __builtin_amdgcn_mfma_f32_16x16x32_bf16(
                                Af[f2][kh], Bf[fc][kh], acc[2*p+f2][fc], 0,0,0);
      __builtin_amdgcn_s_setprio(0);
    }
  }

  float bias_n[4];
  #pragma unroll
  for (int fc=0;fc<4;fc++) bias_n[fc] = bias[Cn + wc*64 + fc*16 + li];
  #pragma unroll
  for (int fr=0;fr<8;fr++){
    int row = R + wr*128 + fr*16 + g*4;
    #pragma unroll
    for (int fc=0;fc<4;fc++){
      long col = (long)by*256 + wc*64 + fc*16 + li;
      #pragma unroll
      for (int r=0;r<4;r++)
        Y[(long)(row+r)*9216 + col] = f2bf(acc[fr][fc][r] + bias_n[fc]);
    }
  }
}

// ---------------- fused RMSNorm + RoPE postprocess (round-5 proven) ----------------
__global__ void k_ppqk(const unsigned short* __restrict__ Y, int ystr, int yoff,
    const float* __restrict__ nw,
    const float* __restrict__ cs, const float* __restrict__ sn, unsigned short* __restrict__ dst,
    int T_log2, int tpb_log2, int dest_off, int S, int no_batch,
    int pos_off, int pos_mask, float qscale)
{
  int rid = blockIdx.x*4 + (threadIdx.x>>6);
  int l = threadIdx.x & 63;
  int h = rid >> T_log2, tk = rid & ((1<<T_log2)-1);
  unsigned pair = *(const unsigned*)(Y + (long)tk*ystr + yoff + h*128 + 2*l);
  float x0 = bf2f((unsigned short)(pair&0xffff));
  float x1 = bf2f((unsigned short)(pair>>16));
  float ss = x0*x0 + x1*x1;
  #pragma unroll
  for (int m=1;m<64;m<<=1) ss += __shfl_xor(ss, m);
  float rr = rsqrtf(ss*(1.0f/128.0f) + 1e-6f);
  x0 *= rr*nw[2*l]; x1 *= rr*nw[2*l+1];
  int p = pos_off + (tk & pos_mask);
  float c0 = cs[p*128 + 2*l], c1 = cs[p*128 + 2*l+1];
  float s0 = sn[p*128 + 2*l], s1 = sn[p*128 + 2*l+1];
  float o0 = (x0*c0 - x1*s0)*qscale;
  float o1 = (x1*c1 + x0*s1)*qscale;
  long idx;
  if (no_batch) idx = (long)h*S + tk;
  else {
    int b = tk >> tpb_log2;
    int sq = dest_off + (tk & ((1<<tpb_log2)-1));
    idx = (long)(b*24+h)*S + sq;
  }
  unsigned out = (unsigned)f2bf(o0) | ((unsigned)f2bf(o1)<<16);
  *(unsigned*)(dst + idx*128 + 2*l) = out;
}

// ---------------- V reorder + transpose (round-5 proven) ----------------
__global__ void k_ppv(const unsigned short* __restrict__ Y, int ystr, int yoff,
                      unsigned short* __restrict__ Vt, int vstr, int no_batch)
{
  __shared__ unsigned short tileS[64][136];
  int t = threadIdx.x, h = blockIdx.y;
  int tile0 = blockIdx.x*64;
  #pragma unroll
  for (int c=0;c<4;c++){
    int j = c*16 + (t>>4), col = (t&15)*8;
    *(u16x8*)&tileS[j][col] = *(const u16x8*)(Y + (long)(tile0+j)*ystr + yoff + h*128 + col);
  }
  __syncthreads();
  int d = t>>1, half = t&1;
  unsigned short tmp[32];
  #pragma unroll
  for (int i=0;i<32;i++) tmp[i] = tileS[half*32+i][d];
  long base;
  if (no_batch) base = ((long)h*128 + d)*vstr + tile0 + half*32;
  else { int b = tile0>>9; base = ((long)(b*24+h)*128 + d)*vstr + (tile0&511) + half*32; }
  #pragma unroll
  for (int k=0;k<4;k++) *(u16x8*)(Vt + base + k*8) = *(const u16x8*)&tmp[k*8];
}

// ---------------- fused-epilogue 128sq QKV GEMM (fallback path) ----------------
__global__ __launch_bounds__(256) void k_gemmP(
    const unsigned short* __restrict__ X,
    const unsigned short* __restrict__ Wimg, const unsigned short* __restrict__ Wenc,
    const float* __restrict__ b0, const float* __restrict__ b1, const float* __restrict__ b2,
    const float* __restrict__ b3, const float* __restrict__ b4, const float* __restrict__ b5,
    const float* __restrict__ nq_, const float* __restrict__ nk_,
    const float* __restrict__ naq_, const float* __restrict__ nak_,
    const float* __restrict__ cs, const float* __restrict__ sn,
    unsigned short* __restrict__ Qd,
    unsigned short* __restrict__ Kdi, unsigned short* __restrict__ Kde,
    unsigned short* __restrict__ Vdi, unsigned short* __restrict__ Vde,
    int rows_img)
{
  const int K = 3072;
  __shared__ unsigned short SH[16384];
  unsigned short (*As)[4096] = (unsigned short(*)[4096])SH;
  unsigned short (*Bs)[4096] = (unsigned short(*)[4096])(SH + 8192);
  const int t = threadIdx.x, w = t>>6, l = t&63;
  const int li = l&15, g = l>>4;
  const int by = blockIdx.y, bx = blockIdx.x;
  const int sec = by>=48 ? 2 : (by>=24 ? 1 : 0);
  const int hd = by - sec*24;
  const int Cl = hd*128;
  const int R = bx*128;
  const bool img = (R < rows_img);
  const unsigned short* Wp = (img ? Wimg : Wenc) + (long)sec*9437184 + (long)Cl*K;
  const float* bias = img ? ((sec==0)?b0:(sec==1)?b1:b2)
                          : ((sec==0)?b3:(sec==1)?b4:b5);
  const int wr = w>>1, wc = w&1;
  f32x4 acc[4][4] = {};

  auto stage = [&](int buf, int kt){
    const int k0 = kt*32;
    #pragma unroll
    for (int c=0;c<2;c++){
      int row = c*64 + (t>>2);
      int scol = ((t&3)<<3) ^ ((row&3)<<3) ^ (((row>>3)&1)<<4);
      gll16(X + (long)(R+row)*K + k0 + scol, &As[buf][c*2048 + w*512]);
      gll16(Wp + (long)row*K + k0 + scol, &Bs[buf][c*2048 + w*512]);
    }
  };

  stage(0,0);
  int buf = 0;
  for (int kt=0; kt<96; kt++){
    __syncthreads();
    if (kt+1 < 96) stage(buf^1, kt+1);
    bf16x8 a[4], b[4];
    #pragma unroll
    for (int m=0;m<4;m++){
      int ar = wr*64 + m*16 + li;
      int ac = (g<<3) ^ ((ar&3)<<3) ^ (((ar>>3)&1)<<4);
      a[m] = *(const bf16x8*)&As[buf][ar*32 + ac];
      int br = wc*64 + m*16 + li;
      int bc2 = (g<<3) ^ ((br&3)<<3) ^ (((br>>3)&1)<<4);
      b[m] = *(const bf16x8*)&Bs[buf][br*32 + bc2];
    }
    #pragma unroll
    for (int m=0;m<4;m++)
      #pragma unroll
      for (int n=0;n<4;n++)
        acc[m][n] = __builtin_amdgcn_mfma_f32_16x16x32_bf16(a[m], b[n], acc[m][n], 0,0,0);
    buf ^= 1;
  }

  float bias_n[4];
  #pragma unroll
  for (int n=0;n<4;n++) bias_n[n] = bias[Cl + wc*64 + n*16 + li];

  if (sec == 2){
    unsigned short* SHT = SH;
    unsigned short* Vd = img ? Vdi : Vde;
    #pragma unroll
    for (int pass=0; pass<2; pass++){
      __syncthreads();
      if (wc == pass){
        #pragma unroll
        for (int m=0;m<4;m++){
          int tok_l = wr*64 + m*16 + (g<<2);
          #pragma unroll
          for (int n=0;n<4;n++){
            int col_loc = n*16 + li;
            u16x4 v4 = { f2bf(acc[m][n][0]+bias_n[n]), f2bf(acc[m][n][1]+bias_n[n]),
                         f2bf(acc[m][n][2]+bias_n[n]), f2bf(acc[m][n][3]+bias_n[n]) };
            *(u16x4*)&SHT[col_loc*136 + tok_l] = v4;
          }
        }
      }
      __syncthreads();
      int d_loc = t>>2, qtr = t&3;
      int d = pass*64 + d_loc;
      int tok0 = R + qtr*32;
      long base;
      if (img) base = ((long)hd*128 + d)*2048 + tok0;
      else { int t2 = tok0 - rows_img; int b_ = t2>>9, s_ = t2&511;
             base = ((long)(b_*24+hd)*128 + d)*512 + s_; }
      #pragma unroll
      for (int k2=0;k2<4;k2++)
        *(u16x8*)(Vd + base + k2*8) = *(const u16x8*)&SHT[d_loc*136 + qtr*32 + k2*8];
    }
    return;
  }

  float part[4][4];
  #pragma unroll
  for (int m=0;m<4;m++)
    #pragma unroll
    for (int r=0;r<4;r++){
      float s_ = 0.f;
      #pragma unroll
      for (int n=0;n<4;n++){ float v = acc[m][n][r] + bias_n[n]; s_ += v*v; }
      part[m][r] = s_;
    }
  #pragma unroll
  for (int m=0;m<4;m++)
    #pragma unroll
    for (int r=0;r<4;r++){
      part[m][r] += __shfl_xor(part[m][r], 1);
      part[m][r] += __shfl_xor(part[m][r], 2);
      part[m][r] += __shfl_xor(part[m][r], 4);
      part[m][r] += __shfl_xor(part[m][r], 8);
    }
  __syncthreads();
  float* rs = (float*)SH;
  if (li == 0){
    #pragma unroll
    for (int m=0;m<4;m++)
      #pragma unroll
      for (int r=0;r<4;r++)
        rs[(wc*2+wr)*64 + m*16 + g*4 + r] = part[m][r];
  }
  __syncthreads();
  float fac[4][4];
  #pragma unroll
  for (int m=0;m<4;m++)
    #pragma unroll
    for (int r=0;r<4;r++){
      int idx = m*16 + g*4 + r;
      float tot = rs[(0*2+wr)*64 + idx] + rs[(1*2+wr)*64 + idx];
      fac[m][r] = rsqrtf(tot*(1.0f/128.0f) + 1e-6f);
    }

  const float* nw = (sec==0) ? (img ? nq_ : naq_) : (img ? nk_ : nak_);
  const float qs = (sec==0) ? (float)(0.08838834764831845 * 1.4426950408889634) : 1.0f;
  float nw_n[4];
  #pragma unroll
  for (int n=0;n<4;n++) nw_n[n] = nw[wc*64 + n*16 + li];

  unsigned short* Kd = img ? Kdi : Kde;

  #pragma unroll
  for (int m=0;m<4;m++){
    #pragma unroll
    for (int r=0;r<4;r++){
      int row_l = wr*64 + m*16 + g*4 + r;
      int t_row = R + row_l;
      int b_, s_, p_;
      if (img){ b_ = t_row>>10; s_ = t_row&1023; p_ = 512+s_; }
      else { int t2 = t_row - rows_img; b_ = t2>>9; s_ = t2&511; p_ = s_; }
      long didx;
      if (sec==0) didx = (long)(b_*24+hd)*1536 + (img ? 512+s_ : s_);
      else        didx = img ? ((long)hd*2048 + t_row) : ((long)(b_*24+hd)*512 + s_);
      const float* crow = cs + (long)p_*128;
      const float* srow = sn + (long)p_*128;
      unsigned short* drow = ((sec==0)?Qd:Kd) + didx*128;
      #pragma unroll
      for (int n=0;n<4;n++){
        int cl = wc*64 + n*16 + li;
        float x = (acc[m][n][r] + bias_n[n]) * fac[m][r] * nw_n[n];
        float xo = __shfl_xor(x, 1);
        float o_ = x*crow[cl] + ((l&1) ? xo*srow[cl] : -xo*srow[cl]);
        drow[cl] = f2bf(o_*qs);
      }
    }
  }
}

// ---------------- fused output GEMM (block-diagonal over rows) ----------------
__global__ __launch_bounds__(256) void k_gemmO(
    const unsigned short* __restrict__ X, const unsigned short* __restrict__ Wf,
    float* __restrict__ out, const float* __restrict__ bo, const float* __restrict__ bao)
{
  const int K = 3072;
  __shared__ unsigned short As[2][4096];
  __shared__ unsigned short Bs[2][4096];
  const int t = threadIdx.x, w = t>>6, l = t&63;
  unsigned wid = blockIdx.x + 24u*blockIdx.y;
  unsigned xc = wid & 7, ii = wid >> 3;
  unsigned xg = xc & 1, yg = xc >> 1;
  int bx = (int)(xg*12 + ii%12);
  int by = (int)(yg*6 + ii/12);
  const bool enc = bx >= 16;
  const unsigned short* Wp = Wf + (enc ? 9437184 : 0);
  const float* bias = enc ? bao : bo;
  const int R = bx*128, C = by*128;
  long xbase, obase;
  if (!enc){ xbase = (long)(R>>10)*1536 + 512 + (R&1023); obase = (long)R*3072; }
  else { int Rp = R-2048; xbase = (long)(Rp>>9)*1536 + (Rp&511); obase = 6291456 + (long)Rp*3072; }
  const int wr = w>>1, wc = w&1;
  f32x4 acc[4][4] = {};

  auto stage = [&](int buf, int kt){
    const int k0 = kt*32;
    #pragma unroll
    for (int c=0;c<2;c++){
      int row = c*64 + (t>>2);
      int scol = ((t&3)<<3) ^ ((row&3)<<3) ^ (((row>>3)&1)<<4);
      gll16(X + (xbase+row)*K + k0 + scol, &As[buf][c*2048 + w*512]);
      gll16(Wp + (long)(C+row)*K + k0 + scol, &Bs[buf][c*2048 + w*512]);
    }
  };

  stage(0,0);
  int buf = 0;
  for (int kt=0; kt<96; kt++){
    __syncthreads();
    if (kt+1 < 96) stage(buf^1, kt+1);
    bf16x8 a[4], b[4];
    #pragma unroll
    for (int m=0;m<4;m++){
      int ar = wr*64 + m*16 + (l&15);
      int ac = ((l>>4)<<3) ^ ((ar&3)<<3) ^ (((ar>>3)&1)<<4);
      a[m] = *(const bf16x8*)&As[buf][ar*32 + ac];
      int br = wc*64 + m*16 + (l&15);
      int bc2 = ((l>>4)<<3) ^ ((br&3)<<3) ^ (((br>>3)&1)<<4);
      b[m] = *(const bf16x8*)&Bs[buf][br*32 + bc2];
    }
    #pragma unroll
    for (int m=0;m<4;m++)
      #pragma unroll
      for (int n=0;n<4;n++)
        acc[m][n] = __builtin_amdgcn_mfma_f32_16x16x32_bf16(a[m], b[n], acc[m][n], 0,0,0);
    buf ^= 1;
  }

  #pragma unroll
  for (int m=0;m<4;m++){
    int rl = wr*64 + m*16 + ((l>>4)<<2);
    #pragma unroll
    for (int n=0;n<4;n++){
      int col = C + wc*64 + n*16 + (l&15);
      float bvv = bias[col];
      #pragma unroll
      for (int r=0;r<4;r++)
        out[obase + (long)(rl+r)*3072 + col] = acc[m][n][r] + bvv;
    }
  }
}

// ---------------- flash attention (proven schedule; Ps compacted to [16][64]
// with even-preserving slot XOR -> LDS 40960 B -> 4 blocks/CU) ----------------
__global__ __launch_bounds__(256) void k_attn(
    const unsigned short* __restrict__ Q,
    const unsigned short* __restrict__ Ke, const unsigned short* __restrict__ Ki,
    const unsigned short* __restrict__ Ve, const unsigned short* __restrict__ Vi,
    unsigned short* __restrict__ AO)
{
  __shared__ unsigned short Ks[8192];
  __shared__ unsigned short Vs[8192];
  __shared__ unsigned short Ps[4][1024];       // per-wave [16 q][64 k], slot-XOR swizzled
  const int t = threadIdx.x, w = t>>6, l = t&63;
  unsigned wid = blockIdx.x + 24u*blockIdx.y + 576u*blockIdx.z;
  unsigned xc = wid & 7, ii = wid >> 3;
  int h = (int)(xc*3 + ii/48);
  unsigned rem = ii % 48;
  int b = (int)(rem/24);
  int qx = (int)(rem%24);
  const int bh = b*24 + h;
  const int q0 = qx*64 + w*16;
  const int g = l>>4;

  auto stageK = [&](int jt){
    const unsigned short* ksrc = (jt < 8) ? Ke + ((long)bh*512 + jt*64)*128
                                          : Ki + ((long)h*2048 + (jt-8)*64)*128;
    #pragma unroll
    for (int c=0;c<4;c++){
      int row = c*16 + (t>>4);
      int col = ((t&15)<<3) ^ ((row&7)<<3);
      gll16(ksrc + row*128 + col, &Ks[c*2048 + w*512]);
    }
  };
  auto stageV = [&](int jt){
    const unsigned short* vsrc; long vstr;
    if (jt < 8){ vsrc = Ve + (long)bh*65536 + jt*64; vstr = 512; }
    else { vsrc = Vi + (long)h*262144 + (jt-8)*64; vstr = 2048; }
    #pragma unroll
    for (int c=0;c<4;c++){
      int row = c*32 + (t>>3);
      int col = ((t&7)<<3) ^ ((row&7)<<3);
      gll16(vsrc + (long)row*vstr + col, &Vs[c*2048 + w*512]);
    }
  };

  bf16x8 qf[4];
  {
    const unsigned short* qp = Q + ((long)bh*1536 + q0 + (l&15))*128 + (g<<3);
    #pragma unroll
    for (int kc=0;kc<4;kc++) qf[kc] = *(const bf16x8*)(qp + kc*32);
  }
  f32x4 o[8] = {};
  float mx = -1e30f;
  float ls = 0.f;

  stageK(0);
  for (int jt=0; jt<40; jt++){
    __syncthreads();
    stageV(jt);

    f32x4 sf[4];
    __builtin_amdgcn_s_setprio(1);
    #pragma unroll
    for (int ct=0;ct<4;ct++){
      f32x4 s = {};
      #pragma unroll
      for (int kc=0;kc<4;kc++){
        int krow = ct*16 + (l&15);
        int kcol = (kc*32 + (g<<3)) ^ ((krow&7)<<3);
        bf16x8 kb = *(const bf16x8*)&Ks[krow*128 + kcol];
        s = __builtin_amdgcn_mfma_f32_16x16x32_bf16(kb, qf[kc], s, 0,0,0);
      }
      sf[ct] = s;
    }
    __builtin_amdgcn_s_setprio(0);

    float pm = sf[0][0];
    #pragma unroll
    for (int ct=0;ct<4;ct++)
      #pragma unroll
      for (int r=0;r<4;r++) pm = fmaxf(pm, sf[ct][r]);
    if (!__all(pm <= mx + 8.0f)){
      float tmax = pm;
      tmax = fmaxf(tmax, __shfl_xor(tmax, 16));
      tmax = fmaxf(tmax, __shfl_xor(tmax, 32));
      float mn = fmaxf(mx, tmax);
      float al = exp2f(mx - mn);
      mx = mn;
      ls *= al;
      #pragma unroll
      for (int r=0;r<4;r++){
        float alo = __shfl(al, (l&48) | ((g<<2)+r));
        #pragma unroll
        for (int f=0;f<8;f++) o[f][r] *= alo;
      }
    }
    // P write: slot = ct*4+g holds k=[4*slot,4*slot+4) for row q=l&15;
    // swizzled slot' = slot ^ ((q&7)<<1) (even-preserving, bijective)
    #pragma unroll
    for (int ct=0;ct<4;ct++){
      float p0 = exp2f(sf[ct][0]-mx), p1 = exp2f(sf[ct][1]-mx);
      float p2 = exp2f(sf[ct][2]-mx), p3 = exp2f(sf[ct][3]-mx);
      ls += (p0+p1)+(p2+p3);
      uint2v pk = { cvtpk(p0,p1), cvtpk(p2,p3) };
      *(uint2v*)&Ps[w][(l&15)*64 + (((ct<<2)+g) ^ ((l&7)<<1))*4] = pk;
    }
    __syncthreads();

    if (jt+1 < 40) stageK(jt+1);

    // pa read: k = kc*32+g*8 .. +7 -> slot pair {kc*8+2g, +1}; XOR keeps pair contiguous
    bf16x8 pa[2];
    #pragma unroll
    for (int kc=0;kc<2;kc++)
      pa[kc] = *(const bf16x8*)&Ps[w][(l&15)*64 + (((kc<<3)+(g<<1)) ^ ((l&7)<<1))*4];
    __builtin_amdgcn_s_setprio(1);
    #pragma unroll
    for (int f=0;f<8;f++){
      #pragma unroll
      for (int kc=0;kc<2;kc++){
        int vrow = f*16 + (l&15);
        int vcol = (kc*32 + (g<<3)) ^ ((vrow&7)<<3);
        bf16x8 vb = *(const bf16x8*)&Vs[vrow*64 + vcol];
        o[f] = __builtin_amdgcn_mfma_f32_16x16x32_bf16(pa[kc], vb, o[f], 0,0,0);
      }
    }
    __builtin_amdgcn_s_setprio(0);
  }

  ls += __shfl_xor(ls, 16);
  ls += __shfl_xor(ls, 32);
  #pragma unroll
  for (int r=0;r<4;r++){
    float lso = __shfl(ls, (l&48) | ((g<<2)+r));
    float inv = 1.0f/lso;
    int qrow = q0 + (g<<2) + r;
    #pragma unroll
    for (int f=0;f<8;f++){
      AO[((long)b*1536 + qrow)*3072 + h*128 + f*16 + (l&15)] = f2bf(o[f][r]*inv);
    }
  }
}

// ---------------- host launch ----------------
extern "C" void kernel_launch(void* const* d_in, const int* in_sizes, int n_in,
                              void* d_out, int out_size, void* d_ws, size_t ws_size,
                              hipStream_t stream)
{
  const float* hs  = (const float*)d_in[0];
  const float* ehs = (const float*)d_in[1];
  const float* rc  = (const float*)d_in[2];
  const float* rs_ = (const float*)d_in[3];
  const float* wq = (const float*)d_in[4];  const float* bq = (const float*)d_in[5];
  const float* wk = (const float*)d_in[6];  const float* bk = (const float*)d_in[7];
  const float* wv = (const float*)d_in[8];  const float* bv = (const float*)d_in[9];
  const float* waq= (const float*)d_in[10]; const float* baq= (const float*)d_in[11];
  const float* wak= (const float*)d_in[12]; const float* bak= (const float*)d_in[13];
  const float* wav= (const float*)d_in[14]; const float* bav= (const float*)d_in[15];
  const float* wo = (const float*)d_in[16]; const float* bo = (const float*)d_in[17];
  const float* wao= (const float*)d_in[18]; const float* bao= (const float*)d_in[19];
  const float* nq = (const float*)d_in[20]; const float* nk = (const float*)d_in[21];
  const float* naq= (const float*)d_in[22]; const float* nak= (const float*)d_in[23];

  const float qsc = (float)(0.08838834764831845 * 1.4426950408889634);

  char* p = (char*)d_ws;
  auto alloc = [&](size_t bytes){ char* r = p; p += bytes; return r; };

  if (ws_size >= (size_t)245366784){
    // ---------- main path (245.4 MB) ----------
    unsigned short* Xh = (unsigned short*)alloc(12582912);  // [2048][3072]
    unsigned short* Xe = (unsigned short*)alloc(6291456);   // [1024][3072] (contiguous)
    unsigned short* Wb = (unsigned short*)alloc(113246208); // 6 QKV weight slots bf16
    unsigned short* Yb = (unsigned short*)alloc(56623104);  // [3072][9216]
    unsigned short* Qb = (unsigned short*)alloc(18874368);  // Q [2][24][1536][128]
    unsigned short* Ke = (unsigned short*)alloc(6291456);   // Kenc
    unsigned short* Ki = (unsigned short*)alloc(12582912);  // Kimg
    unsigned short* Ve = (unsigned short*)alloc(6291456);   // Vtenc
    unsigned short* Vi = (unsigned short*)alloc(12582912);  // Vtimg
    unsigned short* AO = Xh;                                // aliases Xh+Xe (dead by attn)
    unsigned short* Ye = Yb + (long)2048*9216;              // enc proj rows
    (void)Xe;

    k_castA6X<<<64512,256,0,stream>>>(wq, wk, wv, waq, wak, wav, hs, ehs, Wb, Xh);

    k_gemmP256<<<dim3(12,36),512,0,stream>>>(Xh, Wb, Wb + (long)3*9437184,
                                             bq, bk, bv, baq, bak, bav, Yb, 2048);

    k_ppqk<<<12288,256,0,stream>>>(Yb, 9216, 0,    nq,  rc, rs_, Qb, 11, 10, 512, 1536, 0, 512, 1023, qsc);
    k_ppqk<<<12288,256,0,stream>>>(Yb, 9216, 3072, nk,  rc, rs_, Ki, 11, 0,  0,   2048, 1, 512, 1023, 1.0f);
    k_ppv<<<dim3(32,24),256,0,stream>>>(Yb, 9216, 6144, Vi, 2048, 1);
    k_ppqk<<<6144,256,0,stream>>>(Ye, 9216, 0,    naq, rc, rs_, Qb, 10, 9, 0, 1536, 0, 0, 511, qsc);
    k_ppqk<<<6144,256,0,stream>>>(Ye, 9216, 3072, nak, rc, rs_, Ke, 10, 9, 0, 512,  0, 0, 511, 1.0f);
    k_ppv<<<dim3(16,24),256,0,stream>>>(Ye, 9216, 6144, Ve, 512, 0);

    k_attn<<<dim3(24,24,2),256,0,stream>>>(Qb, Ke, Ki, Ve, Vi, AO);

    k_castW2<<<18432,256,0,stream>>>(wo, wao, Wb);          // QKV weights dead
    k_gemmO<<<dim3(24,24),256,0,stream>>>(AO, Wb, (float*)d_out, bo, bao);
  } else {
    // ---------- fallback path (132.1 MB): fused-epilogue 128sq pipeline ----------
    unsigned short* Xh = (unsigned short*)alloc(12582912);
    unsigned short* Xe = (unsigned short*)alloc(6291456);
    unsigned short* Wb = (unsigned short*)alloc(56623104);  // 3 slots
    unsigned short* Qb = (unsigned short*)alloc(18874368);
    unsigned short* Ke = (unsigned short*)alloc(6291456);
    unsigned short* Ki = (unsigned short*)alloc(12582912);
    unsigned short* Ve = (unsigned short*)alloc(6291456);
    unsigned short* Vi = (unsigned short*)alloc(12582912);
    unsigned short* AO = Xh;

    k_castX2<<<9216,256,0,stream>>>(hs, ehs, Xh);

    k_cast<<<9216,256,0,stream>>>(wq, Wb, 2359296);
    k_cast<<<9216,256,0,stream>>>(wk, Wb + 9437184, 2359296);
    k_cast<<<9216,256,0,stream>>>(wv, Wb + 18874368, 2359296);
    k_gemmP<<<dim3(16,72),256,0,stream>>>(Xh, Wb, Wb,
                                          bq, bk, bv, bq, bk, bv,
                                          nq, nk, nq, nk, rc, rs_,
                                          Qb, Ki, Ke, Vi, Ve, 1<<28);

    k_cast<<<9216,256,0,stream>>>(waq, Wb, 2359296);
    k_cast<<<9216,256,0,stream>>>(wak, Wb + 9437184, 2359296);
    k_cast<<<9216,256,0,stream>>>(wav, Wb + 18874368, 2359296);
    k_gemmP<<<dim3(8,72),256,0,stream>>>(Xe, Wb, Wb,
                                         baq, bak, bav, baq, bak, bav,
                                         naq, nak, naq, nak, rc, rs_,
                                         Qb, Ki, Ke, Vi, Ve, 0);

    k_attn<<<dim3(24,24,2),256,0,stream>>>(Qb, Ke, Ki, Ve, Vi, AO);

    k_castW2<<<18432,256,0,stream>>>(wo, wao, Wb);
    k_gemmO<<<dim3(24,24),256,0,stream>>>(AO, Wb, (float*)d_out, bo, bao);
  }
}

// Round 19
// 585.241 us; speedup vs baseline: 1.0080x; 1.0080x over previous
//
#include <hip/hip_runtime.h>

typedef __attribute__((ext_vector_type(8))) short bf16x8;
typedef __attribute__((ext_vector_type(8))) unsigned short u16x8;
typedef __attribute__((ext_vector_type(4))) unsigned short u16x4;
typedef __attribute__((ext_vector_type(4))) float f32x4;
typedef __attribute__((ext_vector_type(2))) unsigned uint2v;

#define DEV static __device__ __forceinline__

DEV unsigned short f2bf(float f){
  unsigned u = __float_as_uint(f);
  u += 0x7fff + ((u>>16)&1);
  return (unsigned short)(u>>16);
}
DEV float bf2f(unsigned short b){ return __uint_as_float(((unsigned)b)<<16); }
DEV unsigned cvtpk(float lo, float hi){
  unsigned r;
  asm("v_cvt_pk_bf16_f32 %0, %1, %2" : "=v"(r) : "v"(lo), "v"(hi));
  return r;
}

DEV void gll16(const void* g, void* l){
  __builtin_amdgcn_global_load_lds((__attribute__((address_space(1))) unsigned*)(void*)g,
                                   (__attribute__((address_space(3))) unsigned*)l, 16, 0, 0);
}

// ---------------- cast fp32 -> bf16 (vectorized) ----------------
__global__ void k_cast(const float* __restrict__ x, unsigned short* __restrict__ y, int n4){
  int i = blockIdx.x*256 + threadIdx.x;
  if (i >= n4) return;
  f32x4 v = ((const f32x4*)x)[i];
  u16x4 o = { f2bf(v.x), f2bf(v.y), f2bf(v.z), f2bf(v.w) };
  ((u16x4*)y)[i] = o;
}

// ---------------- 2-segment input cast (fallback path) ----------------
__global__ void k_castX2(const float* __restrict__ s0, const float* __restrict__ s1,
                         unsigned short* __restrict__ y){
  unsigned i = blockIdx.x*256 + threadIdx.x;          // < 2359296
  const float* s = (i < 1572864u) ? s0 : s1;
  unsigned off = (i < 1572864u) ? i : i - 1572864u;
  f32x4 v = ((const f32x4*)s)[off];
  u16x4 o = { f2bf(v.x), f2bf(v.y), f2bf(v.z), f2bf(v.w) };
  ((u16x4*)y)[i] = o;
}

// ---------------- unified cast: 6 QKV weight segs -> Wb, then hs|ehs -> Xc ----------------
__global__ void k_castA6X(const float* __restrict__ s0, const float* __restrict__ s1,
                          const float* __restrict__ s2, const float* __restrict__ s3,
                          const float* __restrict__ s4, const float* __restrict__ s5,
                          const float* __restrict__ xh, const float* __restrict__ xe,
                          unsigned short* __restrict__ Wb, unsigned short* __restrict__ Xc){
  unsigned i = blockIdx.x*256 + threadIdx.x;          // < 6*2359296 + 2359296
  const float* s; unsigned off; unsigned short* dst; unsigned di;
  if (i < 14155776u){
    unsigned seg = i / 2359296u;                      // block-uniform
    off = i - seg*2359296u;
    s = seg==0?s0: seg==1?s1: seg==2?s2: seg==3?s3: seg==4?s4: s5;
    dst = Wb; di = i;
  } else {
    unsigned j = i - 14155776u;                       // < 2359296
    s = (j < 1572864u) ? xh : xe;
    off = (j < 1572864u) ? j : j - 1572864u;
    dst = Xc; di = j;
  }
  f32x4 v = ((const f32x4*)s)[off];
  u16x4 o = { f2bf(v.x), f2bf(v.y), f2bf(v.z), f2bf(v.w) };
  ((u16x4*)dst)[di] = o;
}

// ---------------- 2-segment weight cast (wo/wao) ----------------
__global__ void k_castW2(const float* __restrict__ s0, const float* __restrict__ s1,
                         unsigned short* __restrict__ y){
  unsigned i = blockIdx.x*256 + threadIdx.x;          // < 2*2359296
  unsigned seg = i / 2359296u;
  unsigned off = i - seg*2359296u;
  const float* s = seg==0?s0:s1;
  f32x4 v = ((const f32x4*)s)[off];
  u16x4 o = { f2bf(v.x), f2bf(v.y), f2bf(v.z), f2bf(v.w) };
  ((u16x4*)y)[i] = o;
}

// ================= 256x256 8-wave QKV GEMM (BK=64, depth-1 dbuf) =================
// Round-17 proven (passed, ~175-185 us vs 308 for 128sq).
__global__ __launch_bounds__(512) void k_gemmP256(
    const unsigned short* __restrict__ X,
    const unsigned short* __restrict__ Wimg, const unsigned short* __restrict__ Wenc,
    const float* __restrict__ b0, const float* __restrict__ b1, const float* __restrict__ b2,
    const float* __restrict__ b3, const float* __restrict__ b4, const float* __restrict__ b5,
    unsigned short* __restrict__ Y, int rows_img)
{
  __shared__ unsigned short LDS[2][32768];   // per buf: A[256][64] @0, B[256][64] @16384 (elems)
  const int t = threadIdx.x, w = t>>6, l = t&63;
  const int li = l&15, g = l>>4;
  const int wr = w>>2, wc = w&3;             // 2 (M) x 4 (N) wave grid
  const int bxr = blockIdx.x, by = blockIdx.y;
  const int R = bxr*256;
  const int sec = by/12;                     // Q/K/V section
  const int Cn = (by%12)*256;                // col base within section
  const bool img = (R < rows_img);           // block-uniform
  const unsigned short* Wbase = (img ? Wimg : Wenc) + (long)sec*9437184 + (long)Cn*3072;
  const float* bias = img ? ((sec==0)?b0:(sec==1)?b1:b2)
                          : ((sec==0)?b3:(sec==1)?b4:b5);

  f32x4 acc[8][4] = {};

  auto stageC = [&](int buf, int kt, int c){
    int row = (c&3)*64 + (t>>3);
    int sgrp = (t&7) ^ (row&7);
    const unsigned short* src = (c<4)
        ? X + (long)(R+row)*3072 + kt*64 + sgrp*8
        : Wbase + (long)row*3072 + kt*64 + sgrp*8;
    gll16(src, &LDS[buf][(c<4?0:16384) + (c&3)*4096 + t*8]);
  };

  #pragma unroll
  for (int c=0;c<8;c++) stageC(0, 0, c);     // prologue: tile 0

  for (int kt=0; kt<48; kt++){
    __syncthreads();                         // tile kt resident; buf[(kt+1)&1] free
    const int buf = kt&1;
    const unsigned short* Ab = &LDS[buf][0];
    const unsigned short* Bb = &LDS[buf][16384];

    bf16x8 Bf[4][2];
    #pragma unroll
    for (int fc=0;fc<4;fc++)
      #pragma unroll
      for (int kh=0;kh<2;kh++){
        int brow = wc*64 + fc*16 + li;
        int bgrp = ((kh<<2) + g) ^ (brow&7);
        Bf[fc][kh] = *(const bf16x8*)&Bb[brow*64 + bgrp*8];
      }
    if (kt+1 < 48){
      #pragma unroll
      for (int c=0;c<4;c++) stageC(buf^1, kt+1, c);
    }

    #pragma unroll
    for (int p=0;p<4;p++){
      bf16x8 Af[2][2];
      #pragma unroll
      for (int f2=0;f2<2;f2++)
        #pragma unroll
        for (int kh=0;kh<2;kh++){
          int arow = wr*128 + (2*p+f2)*16 + li;
          int agrp = ((kh<<2) + g) ^ (arow&7);
          Af[f2][kh] = *(const bf16x8*)&Ab[arow*64 + agrp*8];
        }
      if (p==0 && kt+1 < 48){
        #pragma unroll
        for (int c=4;c<8;c++) stageC(buf^1, kt+1, c);
      }
      __builtin_amdgcn_s_setprio(1);
      #pragma unroll
      for (int f2=0;f2<2;f2++)
        #pragma unroll
        for (int fc=0;fc<4;fc++)
          #pragma unroll
          for (int kh=0;kh<2;kh++)
            acc[2*p+f2][fc] = __builtin_amdgcn_mfma_f32_16x16x32_bf16(
                                Af[f2][kh], Bf[fc][kh], acc[2*p+f2][fc], 0,0,0);
      __builtin_amdgcn_s_setprio(0);
    }
  }

  float bias_n[4];
  #pragma unroll
  for (int fc=0;fc<4;fc++) bias_n[fc] = bias[Cn + wc*64 + fc*16 + li];
  #pragma unroll
  for (int fr=0;fr<8;fr++){
    int row = R + wr*128 + fr*16 + g*4;
    #pragma unroll
    for (int fc=0;fc<4;fc++){
      long col = (long)by*256 + wc*64 + fc*16 + li;
      #pragma unroll
      for (int r=0;r<4;r++)
        Y[(long)(row+r)*9216 + col] = f2bf(acc[fr][fc][r] + bias_n[fc]);
    }
  }
}

// ---------------- fused RMSNorm + RoPE postprocess (round-5 proven) ----------------
__global__ void k_ppqk(const unsigned short* __restrict__ Y, int ystr, int yoff,
    const float* __restrict__ nw,
    const float* __restrict__ cs, const float* __restrict__ sn, unsigned short* __restrict__ dst,
    int T_log2, int tpb_log2, int dest_off, int S, int no_batch,
    int pos_off, int pos_mask, float qscale)
{
  int rid = blockIdx.x*4 + (threadIdx.x>>6);
  int l = threadIdx.x & 63;
  int h = rid >> T_log2, tk = rid & ((1<<T_log2)-1);
  unsigned pair = *(const unsigned*)(Y + (long)tk*ystr + yoff + h*128 + 2*l);
  float x0 = bf2f((unsigned short)(pair&0xffff));
  float x1 = bf2f((unsigned short)(pair>>16));
  float ss = x0*x0 + x1*x1;
  #pragma unroll
  for (int m=1;m<64;m<<=1) ss += __shfl_xor(ss, m);
  float rr = rsqrtf(ss*(1.0f/128.0f) + 1e-6f);
  x0 *= rr*nw[2*l]; x1 *= rr*nw[2*l+1];
  int p = pos_off + (tk & pos_mask);
  float c0 = cs[p*128 + 2*l], c1 = cs[p*128 + 2*l+1];
  float s0 = sn[p*128 + 2*l], s1 = sn[p*128 + 2*l+1];
  float o0 = (x0*c0 - x1*s0)*qscale;
  float o1 = (x1*c1 + x0*s1)*qscale;
  long idx;
  if (no_batch) idx = (long)h*S + tk;
  else {
    int b = tk >> tpb_log2;
    int sq = dest_off + (tk & ((1<<tpb_log2)-1));
    idx = (long)(b*24+h)*S + sq;
  }
  unsigned out = (unsigned)f2bf(o0) | ((unsigned)f2bf(o1)<<16);
  *(unsigned*)(dst + idx*128 + 2*l) = out;
}

// ---------------- V reorder + transpose (round-5 proven) ----------------
__global__ void k_ppv(const unsigned short* __restrict__ Y, int ystr, int yoff,
                      unsigned short* __restrict__ Vt, int vstr, int no_batch)
{
  __shared__ unsigned short tileS[64][136];
  int t = threadIdx.x, h = blockIdx.y;
  int tile0 = blockIdx.x*64;
  #pragma unroll
  for (int c=0;c<4;c++){
    int j = c*16 + (t>>4), col = (t&15)*8;
    *(u16x8*)&tileS[j][col] = *(const u16x8*)(Y + (long)(tile0+j)*ystr + yoff + h*128 + col);
  }
  __syncthreads();
  int d = t>>1, half = t&1;
  unsigned short tmp[32];
  #pragma unroll
  for (int i=0;i<32;i++) tmp[i] = tileS[half*32+i][d];
  long base;
  if (no_batch) base = ((long)h*128 + d)*vstr + tile0 + half*32;
  else { int b = tile0>>9; base = ((long)(b*24+h)*128 + d)*vstr + (tile0&511) + half*32; }
  #pragma unroll
  for (int k=0;k<4;k++) *(u16x8*)(Vt + base + k*8) = *(const u16x8*)&tmp[k*8];
}

// ---------------- fused-epilogue 128sq QKV GEMM (fallback path) ----------------
__global__ __launch_bounds__(256) void k_gemmP(
    const unsigned short* __restrict__ X,
    const unsigned short* __restrict__ Wimg, const unsigned short* __restrict__ Wenc,
    const float* __restrict__ b0, const float* __restrict__ b1, const float* __restrict__ b2,
    const float* __restrict__ b3, const float* __restrict__ b4, const float* __restrict__ b5,
    const float* __restrict__ nq_, const float* __restrict__ nk_,
    const float* __restrict__ naq_, const float* __restrict__ nak_,
    const float* __restrict__ cs, const float* __restrict__ sn,
    unsigned short* __restrict__ Qd,
    unsigned short* __restrict__ Kdi, unsigned short* __restrict__ Kde,
    unsigned short* __restrict__ Vdi, unsigned short* __restrict__ Vde,
    int rows_img)
{
  const int K = 3072;
  __shared__ unsigned short SH[16384];
  unsigned short (*As)[4096] = (unsigned short(*)[4096])SH;
  unsigned short (*Bs)[4096] = (unsigned short(*)[4096])(SH + 8192);
  const int t = threadIdx.x, w = t>>6, l = t&63;
  const int li = l&15, g = l>>4;
  const int by = blockIdx.y, bx = blockIdx.x;
  const int sec = by>=48 ? 2 : (by>=24 ? 1 : 0);
  const int hd = by - sec*24;
  const int Cl = hd*128;
  const int R = bx*128;
  const bool img = (R < rows_img);
  const unsigned short* Wp = (img ? Wimg : Wenc) + (long)sec*9437184 + (long)Cl*K;
  const float* bias = img ? ((sec==0)?b0:(sec==1)?b1:b2)
                          : ((sec==0)?b3:(sec==1)?b4:b5);
  const int wr = w>>1, wc = w&1;
  f32x4 acc[4][4] = {};

  auto stage = [&](int buf, int kt){
    const int k0 = kt*32;
    #pragma unroll
    for (int c=0;c<2;c++){
      int row = c*64 + (t>>2);
      int scol = ((t&3)<<3) ^ ((row&3)<<3) ^ (((row>>3)&1)<<4);
      gll16(X + (long)(R+row)*K + k0 + scol, &As[buf][c*2048 + w*512]);
      gll16(Wp + (long)row*K + k0 + scol, &Bs[buf][c*2048 + w*512]);
    }
  };

  stage(0,0);
  int buf = 0;
  for (int kt=0; kt<96; kt++){
    __syncthreads();
    if (kt+1 < 96) stage(buf^1, kt+1);
    bf16x8 a[4], b[4];
    #pragma unroll
    for (int m=0;m<4;m++){
      int ar = wr*64 + m*16 + li;
      int ac = (g<<3) ^ ((ar&3)<<3) ^ (((ar>>3)&1)<<4);
      a[m] = *(const bf16x8*)&As[buf][ar*32 + ac];
      int br = wc*64 + m*16 + li;
      int bc2 = (g<<3) ^ ((br&3)<<3) ^ (((br>>3)&1)<<4);
      b[m] = *(const bf16x8*)&Bs[buf][br*32 + bc2];
    }
    #pragma unroll
    for (int m=0;m<4;m++)
      #pragma unroll
      for (int n=0;n<4;n++)
        acc[m][n] = __builtin_amdgcn_mfma_f32_16x16x32_bf16(a[m], b[n], acc[m][n], 0,0,0);
    buf ^= 1;
  }

  float bias_n[4];
  #pragma unroll
  for (int n=0;n<4;n++) bias_n[n] = bias[Cl + wc*64 + n*16 + li];

  if (sec == 2){
    unsigned short* SHT = SH;
    unsigned short* Vd = img ? Vdi : Vde;
    #pragma unroll
    for (int pass=0; pass<2; pass++){
      __syncthreads();
      if (wc == pass){
        #pragma unroll
        for (int m=0;m<4;m++){
          int tok_l = wr*64 + m*16 + (g<<2);
          #pragma unroll
          for (int n=0;n<4;n++){
            int col_loc = n*16 + li;
            u16x4 v4 = { f2bf(acc[m][n][0]+bias_n[n]), f2bf(acc[m][n][1]+bias_n[n]),
                         f2bf(acc[m][n][2]+bias_n[n]), f2bf(acc[m][n][3]+bias_n[n]) };
            *(u16x4*)&SHT[col_loc*136 + tok_l] = v4;
          }
        }
      }
      __syncthreads();
      int d_loc = t>>2, qtr = t&3;
      int d = pass*64 + d_loc;
      int tok0 = R + qtr*32;
      long base;
      if (img) base = ((long)hd*128 + d)*2048 + tok0;
      else { int t2 = tok0 - rows_img; int b_ = t2>>9, s_ = t2&511;
             base = ((long)(b_*24+hd)*128 + d)*512 + s_; }
      #pragma unroll
      for (int k2=0;k2<4;k2++)
        *(u16x8*)(Vd + base + k2*8) = *(const u16x8*)&SHT[d_loc*136 + qtr*32 + k2*8];
    }
    return;
  }

  float part[4][4];
  #pragma unroll
  for (int m=0;m<4;m++)
    #pragma unroll
    for (int r=0;r<4;r++){
      float s_ = 0.f;
      #pragma unroll
      for (int n=0;n<4;n++){ float v = acc[m][n][r] + bias_n[n]; s_ += v*v; }
      part[m][r] = s_;
    }
  #pragma unroll
  for (int m=0;m<4;m++)
    #pragma unroll
    for (int r=0;r<4;r++){
      part[m][r] += __shfl_xor(part[m][r], 1);
      part[m][r] += __shfl_xor(part[m][r], 2);
      part[m][r] += __shfl_xor(part[m][r], 4);
      part[m][r] += __shfl_xor(part[m][r], 8);
    }
  __syncthreads();
  float* rs = (float*)SH;
  if (li == 0){
    #pragma unroll
    for (int m=0;m<4;m++)
      #pragma unroll
      for (int r=0;r<4;r++)
        rs[(wc*2+wr)*64 + m*16 + g*4 + r] = part[m][r];
  }
  __syncthreads();
  float fac[4][4];
  #pragma unroll
  for (int m=0;m<4;m++)
    #pragma unroll
    for (int r=0;r<4;r++){
      int idx = m*16 + g*4 + r;
      float tot = rs[(0*2+wr)*64 + idx] + rs[(1*2+wr)*64 + idx];
      fac[m][r] = rsqrtf(tot*(1.0f/128.0f) + 1e-6f);
    }

  const float* nw = (sec==0) ? (img ? nq_ : naq_) : (img ? nk_ : nak_);
  const float qs = (sec==0) ? (float)(0.08838834764831845 * 1.4426950408889634) : 1.0f;
  float nw_n[4];
  #pragma unroll
  for (int n=0;n<4;n++) nw_n[n] = nw[wc*64 + n*16 + li];

  unsigned short* Kd = img ? Kdi : Kde;

  #pragma unroll
  for (int m=0;m<4;m++){
    #pragma unroll
    for (int r=0;r<4;r++){
      int row_l = wr*64 + m*16 + g*4 + r;
      int t_row = R + row_l;
      int b_, s_, p_;
      if (img){ b_ = t_row>>10; s_ = t_row&1023; p_ = 512+s_; }
      else { int t2 = t_row - rows_img; b_ = t2>>9; s_ = t2&511; p_ = s_; }
      long didx;
      if (sec==0) didx = (long)(b_*24+hd)*1536 + (img ? 512+s_ : s_);
      else        didx = img ? ((long)hd*2048 + t_row) : ((long)(b_*24+hd)*512 + s_);
      const float* crow = cs + (long)p_*128;
      const float* srow = sn + (long)p_*128;
      unsigned short* drow = ((sec==0)?Qd:Kd) + didx*128;
      #pragma unroll
      for (int n=0;n<4;n++){
        int cl = wc*64 + n*16 + li;
        float x = (acc[m][n][r] + bias_n[n]) * fac[m][r] * nw_n[n];
        float xo = __shfl_xor(x, 1);
        float o_ = x*crow[cl] + ((l&1) ? xo*srow[cl] : -xo*srow[cl]);
        drow[cl] = f2bf(o_*qs);
      }
    }
  }
}

// ---------------- fused output GEMM (block-diagonal over rows) ----------------
__global__ __launch_bounds__(256) void k_gemmO(
    const unsigned short* __restrict__ X, const unsigned short* __restrict__ Wf,
    float* __restrict__ out, const float* __restrict__ bo, const float* __restrict__ bao)
{
  const int K = 3072;
  __shared__ unsigned short As[2][4096];
  __shared__ unsigned short Bs[2][4096];
  const int t = threadIdx.x, w = t>>6, l = t&63;
  unsigned wid = blockIdx.x + 24u*blockIdx.y;
  unsigned xc = wid & 7, ii = wid >> 3;
  unsigned xg = xc & 1, yg = xc >> 1;
  int bx = (int)(xg*12 + ii%12);
  int by = (int)(yg*6 + ii/12);
  const bool enc = bx >= 16;
  const unsigned short* Wp = Wf + (enc ? 9437184 : 0);
  const float* bias = enc ? bao : bo;
  const int R = bx*128, C = by*128;
  long xbase, obase;
  if (!enc){ xbase = (long)(R>>10)*1536 + 512 + (R&1023); obase = (long)R*3072; }
  else { int Rp = R-2048; xbase = (long)(Rp>>9)*1536 + (Rp&511); obase = 6291456 + (long)Rp*3072; }
  const int wr = w>>1, wc = w&1;
  f32x4 acc[4][4] = {};

  auto stage = [&](int buf, int kt){
    const int k0 = kt*32;
    #pragma unroll
    for (int c=0;c<2;c++){
      int row = c*64 + (t>>2);
      int scol = ((t&3)<<3) ^ ((row&3)<<3) ^ (((row>>3)&1)<<4);
      gll16(X + (xbase+row)*K + k0 + scol, &As[buf][c*2048 + w*512]);
      gll16(Wp + (long)(C+row)*K + k0 + scol, &Bs[buf][c*2048 + w*512]);
    }
  };

  stage(0,0);
  int buf = 0;
  for (int kt=0; kt<96; kt++){
    __syncthreads();
    if (kt+1 < 96) stage(buf^1, kt+1);
    bf16x8 a[4], b[4];
    #pragma unroll
    for (int m=0;m<4;m++){
      int ar = wr*64 + m*16 + (l&15);
      int ac = ((l>>4)<<3) ^ ((ar&3)<<3) ^ (((ar>>3)&1)<<4);
      a[m] = *(const bf16x8*)&As[buf][ar*32 + ac];
      int br = wc*64 + m*16 + (l&15);
      int bc2 = ((l>>4)<<3) ^ ((br&3)<<3) ^ (((br>>3)&1)<<4);
      b[m] = *(const bf16x8*)&Bs[buf][br*32 + bc2];
    }
    #pragma unroll
    for (int m=0;m<4;m++)
      #pragma unroll
      for (int n=0;n<4;n++)
        acc[m][n] = __builtin_amdgcn_mfma_f32_16x16x32_bf16(a[m], b[n], acc[m][n], 0,0,0);
    buf ^= 1;
  }

  #pragma unroll
  for (int m=0;m<4;m++){
    int rl = wr*64 + m*16 + ((l>>4)<<2);
    #pragma unroll
    for (int n=0;n<4;n++){
      int col = C + wc*64 + n*16 + (l&15);
      float bvv = bias[col];
      #pragma unroll
      for (int r=0;r<4;r++)
        out[obase + (long)(rl+r)*3072 + col] = acc[m][n][r] + bvv;
    }
  }
}

// ---------------- flash attention (round-17 proven: Ps [16][88] padded) ----------------
__global__ __launch_bounds__(256) void k_attn(
    const unsigned short* __restrict__ Q,
    const unsigned short* __restrict__ Ke, const unsigned short* __restrict__ Ki,
    const unsigned short* __restrict__ Ve, const unsigned short* __restrict__ Vi,
    unsigned short* __restrict__ AO)
{
  __shared__ unsigned short Ks[8192];
  __shared__ unsigned short Vs[8192];
  __shared__ unsigned short Ps[4][1408];
  const int t = threadIdx.x, w = t>>6, l = t&63;
  unsigned wid = blockIdx.x + 24u*blockIdx.y + 576u*blockIdx.z;
  unsigned xc = wid & 7, ii = wid >> 3;
  int h = (int)(xc*3 + ii/48);
  unsigned rem = ii % 48;
  int b = (int)(rem/24);
  int qx = (int)(rem%24);
  const int bh = b*24 + h;
  const int q0 = qx*64 + w*16;
  const int g = l>>4;

  auto stageK = [&](int jt){
    const unsigned short* ksrc = (jt < 8) ? Ke + ((long)bh*512 + jt*64)*128
                                          : Ki + ((long)h*2048 + (jt-8)*64)*128;
    #pragma unroll
    for (int c=0;c<4;c++){
      int row = c*16 + (t>>4);
      int col = ((t&15)<<3) ^ ((row&7)<<3);
      gll16(ksrc + row*128 + col, &Ks[c*2048 + w*512]);
    }
  };
  auto stageV = [&](int jt){
    const unsigned short* vsrc; long vstr;
    if (jt < 8){ vsrc = Ve + (long)bh*65536 + jt*64; vstr = 512; }
    else { vsrc = Vi + (long)h*262144 + (jt-8)*64; vstr = 2048; }
    #pragma unroll
    for (int c=0;c<4;c++){
      int row = c*32 + (t>>3);
      int col = ((t&7)<<3) ^ ((row&7)<<3);
      gll16(vsrc + (long)row*vstr + col, &Vs[c*2048 + w*512]);
    }
  };

  bf16x8 qf[4];
  {
    const unsigned short* qp = Q + ((long)bh*1536 + q0 + (l&15))*128 + (g<<3);
    #pragma unroll
    for (int kc=0;kc<4;kc++) qf[kc] = *(const bf16x8*)(qp + kc*32);
  }
  f32x4 o[8] = {};
  float mx = -1e30f;
  float ls = 0.f;

  stageK(0);
  for (int jt=0; jt<40; jt++){
    __syncthreads();
    stageV(jt);

    f32x4 sf[4];
    __builtin_amdgcn_s_setprio(1);
    #pragma unroll
    for (int ct=0;ct<4;ct++){
      f32x4 s = {};
      #pragma unroll
      for (int kc=0;kc<4;kc++){
        int krow = ct*16 + (l&15);
        int kcol = (kc*32 + (g<<3)) ^ ((krow&7)<<3);
        bf16x8 kb = *(const bf16x8*)&Ks[krow*128 + kcol];
        s = __builtin_amdgcn_mfma_f32_16x16x32_bf16(kb, qf[kc], s, 0,0,0);
      }
      sf[ct] = s;
    }
    __builtin_amdgcn_s_setprio(0);

    float pm = sf[0][0];
    #pragma unroll
    for (int ct=0;ct<4;ct++)
      #pragma unroll
      for (int r=0;r<4;r++) pm = fmaxf(pm, sf[ct][r]);
    if (!__all(pm <= mx + 8.0f)){
      float tmax = pm;
      tmax = fmaxf(tmax, __shfl_xor(tmax, 16));
      tmax = fmaxf(tmax, __shfl_xor(tmax, 32));
      float mn = fmaxf(mx, tmax);
      float al = exp2f(mx - mn);
      mx = mn;
      ls *= al;
      #pragma unroll
      for (int r=0;r<4;r++){
        float alo = __shfl(al, (l&48) | ((g<<2)+r));
        #pragma unroll
        for (int f=0;f<8;f++) o[f][r] *= alo;
      }
    }
    #pragma unroll
    for (int ct=0;ct<4;ct++){
      float p0 = exp2f(sf[ct][0]-mx), p1 = exp2f(sf[ct][1]-mx);
      float p2 = exp2f(sf[ct][2]-mx), p3 = exp2f(sf[ct][3]-mx);
      ls += (p0+p1)+(p2+p3);
      uint2v pk = { cvtpk(p0,p1), cvtpk(p2,p3) };
      *(uint2v*)&Ps[w][(l&15)*88 + ct*16 + (g<<2)] = pk;
    }
    __syncthreads();

    if (jt+1 < 40) stageK(jt+1);

    bf16x8 pa[2];
    #pragma unroll
    for (int kc=0;kc<2;kc++)
      pa[kc] = *(const bf16x8*)&Ps[w][(l&15)*88 + kc*32 + (g<<3)];
    __builtin_amdgcn_s_setprio(1);
    #pragma unroll
    for (int f=0;f<8;f++){
      #pragma unroll
      for (int kc=0;kc<2;kc++){
        int vrow = f*16 + (l&15);
        int vcol = (kc*32 + (g<<3)) ^ ((vrow&7)<<3);
        bf16x8 vb = *(const bf16x8*)&Vs[vrow*64 + vcol];
        o[f] = __builtin_amdgcn_mfma_f32_16x16x32_bf16(pa[kc], vb, o[f], 0,0,0);
      }
    }
    __builtin_amdgcn_s_setprio(0);
  }

  ls += __shfl_xor(ls, 16);
  ls += __shfl_xor(ls, 32);
  #pragma unroll
  for (int r=0;r<4;r++){
    float lso = __shfl(ls, (l&48) | ((g<<2)+r));
    float inv = 1.0f/lso;
    int qrow = q0 + (g<<2) + r;
    #pragma unroll
    for (int f=0;f<8;f++){
      AO[((long)b*1536 + qrow)*3072 + h*128 + f*16 + (l&15)] = f2bf(o[f][r]*inv);
    }
  }
}

// ---------------- host launch ----------------
extern "C" void kernel_launch(void* const* d_in, const int* in_sizes, int n_in,
                              void* d_out, int out_size, void* d_ws, size_t ws_size,
                              hipStream_t stream)
{
  const float* hs  = (const float*)d_in[0];
  const float* ehs = (const float*)d_in[1];
  const float* rc  = (const float*)d_in[2];
  const float* rs_ = (const float*)d_in[3];
  const float* wq = (const float*)d_in[4];  const float* bq = (const float*)d_in[5];
  const float* wk = (const float*)d_in[6];  const float* bk = (const float*)d_in[7];
  const float* wv = (const float*)d_in[8];  const float* bv = (const float*)d_in[9];
  const float* waq= (const float*)d_in[10]; const float* baq= (const float*)d_in[11];
  const float* wak= (const float*)d_in[12]; const float* bak= (const float*)d_in[13];
  const float* wav= (const float*)d_in[14]; const float* bav= (const float*)d_in[15];
  const float* wo = (const float*)d_in[16]; const float* bo = (const float*)d_in[17];
  const float* wao= (const float*)d_in[18]; const float* bao= (const float*)d_in[19];
  const float* nq = (const float*)d_in[20]; const float* nk = (const float*)d_in[21];
  const float* naq= (const float*)d_in[22]; const float* nak= (const float*)d_in[23];

  const float qsc = (float)(0.08838834764831845 * 1.4426950408889634);

  char* p = (char*)d_ws;
  auto alloc = [&](size_t bytes){ char* r = p; p += bytes; return r; };

  if (ws_size >= (size_t)245366784){
    // ---------- main path (245.4 MB) ----------
    unsigned short* Xh = (unsigned short*)alloc(12582912);  // [2048][3072]
    unsigned short* Xe = (unsigned short*)alloc(6291456);   // [1024][3072] (contiguous)
    unsigned short* Wb = (unsigned short*)alloc(113246208); // 6 QKV weight slots bf16
    unsigned short* Yb = (unsigned short*)alloc(56623104);  // [3072][9216]
    unsigned short* Qb = (unsigned short*)alloc(18874368);  // Q [2][24][1536][128]
    unsigned short* Ke = (unsigned short*)alloc(6291456);   // Kenc
    unsigned short* Ki = (unsigned short*)alloc(12582912);  // Kimg
    unsigned short* Ve = (unsigned short*)alloc(6291456);   // Vtenc
    unsigned short* Vi = (unsigned short*)alloc(12582912);  // Vtimg
    unsigned short* AO = Xh;                                // aliases Xh+Xe (dead by attn)
    unsigned short* Ye = Yb + (long)2048*9216;              // enc proj rows
    (void)Xe;

    k_castA6X<<<64512,256,0,stream>>>(wq, wk, wv, waq, wak, wav, hs, ehs, Wb, Xh);

    k_gemmP256<<<dim3(12,36),512,0,stream>>>(Xh, Wb, Wb + (long)3*9437184,
                                             bq, bk, bv, baq, bak, bav, Yb, 2048);

    k_ppqk<<<12288,256,0,stream>>>(Yb, 9216, 0,    nq,  rc, rs_, Qb, 11, 10, 512, 1536, 0, 512, 1023, qsc);
    k_ppqk<<<12288,256,0,stream>>>(Yb, 9216, 3072, nk,  rc, rs_, Ki, 11, 0,  0,   2048, 1, 512, 1023, 1.0f);
    k_ppv<<<dim3(32,24),256,0,stream>>>(Yb, 9216, 6144, Vi, 2048, 1);
    k_ppqk<<<6144,256,0,stream>>>(Ye, 9216, 0,    naq, rc, rs_, Qb, 10, 9, 0, 1536, 0, 0, 511, qsc);
    k_ppqk<<<6144,256,0,stream>>>(Ye, 9216, 3072, nak, rc, rs_, Ke, 10, 9, 0, 512,  0, 0, 511, 1.0f);
    k_ppv<<<dim3(16,24),256,0,stream>>>(Ye, 9216, 6144, Ve, 512, 0);

    k_attn<<<dim3(24,24,2),256,0,stream>>>(Qb, Ke, Ki, Ve, Vi, AO);

    k_castW2<<<18432,256,0,stream>>>(wo, wao, Wb);          // QKV weights dead
    k_gemmO<<<dim3(24,24),256,0,stream>>>(AO, Wb, (float*)d_out, bo, bao);
  } else {
    // ---------- fallback path (132.1 MB): fused-epilogue 128sq pipeline ----------
    unsigned short* Xh = (unsigned short*)alloc(12582912);
    unsigned short* Xe = (unsigned short*)alloc(6291456);
    unsigned short* Wb = (unsigned short*)alloc(56623104);  // 3 slots
    unsigned short* Qb = (unsigned short*)alloc(18874368);
    unsigned short* Ke = (unsigned short*)alloc(6291456);
    unsigned short* Ki = (unsigned short*)alloc(12582912);
    unsigned short* Ve = (unsigned short*)alloc(6291456);
    unsigned short* Vi = (unsigned short*)alloc(12582912);
    unsigned short* AO = Xh;

    k_castX2<<<9216,256,0,stream>>>(hs, ehs, Xh);

    k_cast<<<9216,256,0,stream>>>(wq, Wb, 2359296);
    k_cast<<<9216,256,0,stream>>>(wk, Wb + 9437184, 2359296);
    k_cast<<<9216,256,0,stream>>>(wv, Wb + 18874368, 2359296);
    k_gemmP<<<dim3(16,72),256,0,stream>>>(Xh, Wb, Wb,
                                          bq, bk, bv, bq, bk, bv,
                                          nq, nk, nq, nk, rc, rs_,
                                          Qb, Ki, Ke, Vi, Ve, 1<<28);

    k_cast<<<9216,256,0,stream>>>(waq, Wb, 2359296);
    k_cast<<<9216,256,0,stream>>>(wak, Wb + 9437184, 2359296);
    k_cast<<<9216,256,0,stream>>>(wav, Wb + 18874368, 2359296);
    k_gemmP<<<dim3(8,72),256,0,stream>>>(Xe, Wb, Wb,
                                         baq, bak, bav, baq, bak, bav,
                                         naq, nak, naq, nak, rc, rs_,
                                         Qb, Ki, Ke, Vi, Ve, 0);

    k_attn<<<dim3(24,24,2),256,0,stream>>>(Qb, Ke, Ki, Ve, Vi, AO);

    k_castW2<<<18432,256,0,stream>>>(wo, wao, Wb);
    k_gemmO<<<dim3(24,24),256,0,stream>>>(AO, Wb, (float*)d_out, bo, bao);
  }
}

// Round 20
// 580.980 us; speedup vs baseline: 1.0153x; 1.0073x over previous
//
#include <hip/hip_runtime.h>

typedef __attribute__((ext_vector_type(8))) short bf16x8;
typedef __attribute__((ext_vector_type(8))) unsigned short u16x8;
typedef __attribute__((ext_vector_type(4))) unsigned short u16x4;
typedef __attribute__((ext_vector_type(4))) float f32x4;
typedef __attribute__((ext_vector_type(2))) unsigned uint2v;

#define DEV static __device__ __forceinline__

DEV unsigned short f2bf(float f){
  unsigned u = __float_as_uint(f);
  u += 0x7fff + ((u>>16)&1);
  return (unsigned short)(u>>16);
}
DEV float bf2f(unsigned short b){ return __uint_as_float(((unsigned)b)<<16); }
DEV unsigned cvtpk(float lo, float hi){
  unsigned r;
  asm("v_cvt_pk_bf16_f32 %0, %1, %2" : "=v"(r) : "v"(lo), "v"(hi));
  return r;
}

DEV void gll16(const void* g, void* l){
  __builtin_amdgcn_global_load_lds((__attribute__((address_space(1))) unsigned*)(void*)g,
                                   (__attribute__((address_space(3))) unsigned*)l, 16, 0, 0);
}

// ---------------- cast fp32 -> bf16 (vectorized) ----------------
__global__ void k_cast(const float* __restrict__ x, unsigned short* __restrict__ y, int n4){
  int i = blockIdx.x*256 + threadIdx.x;
  if (i >= n4) return;
  f32x4 v = ((const f32x4*)x)[i];
  u16x4 o = { f2bf(v.x), f2bf(v.y), f2bf(v.z), f2bf(v.w) };
  ((u16x4*)y)[i] = o;
}

// ---------------- 2-segment input cast (fallback path) ----------------
__global__ void k_castX2(const float* __restrict__ s0, const float* __restrict__ s1,
                         unsigned short* __restrict__ y){
  unsigned i = blockIdx.x*256 + threadIdx.x;          // < 2359296
  const float* s = (i < 1572864u) ? s0 : s1;
  unsigned off = (i < 1572864u) ? i : i - 1572864u;
  f32x4 v = ((const f32x4*)s)[off];
  u16x4 o = { f2bf(v.x), f2bf(v.y), f2bf(v.z), f2bf(v.w) };
  ((u16x4*)y)[i] = o;
}

// ---------------- unified cast: 6 QKV weight segs -> Wb, then hs|ehs -> Xc ----------------
__global__ void k_castA6X(const float* __restrict__ s0, const float* __restrict__ s1,
                          const float* __restrict__ s2, const float* __restrict__ s3,
                          const float* __restrict__ s4, const float* __restrict__ s5,
                          const float* __restrict__ xh, const float* __restrict__ xe,
                          unsigned short* __restrict__ Wb, unsigned short* __restrict__ Xc){
  unsigned i = blockIdx.x*256 + threadIdx.x;          // < 6*2359296 + 2359296
  const float* s; unsigned off; unsigned short* dst; unsigned di;
  if (i < 14155776u){
    unsigned seg = i / 2359296u;                      // block-uniform
    off = i - seg*2359296u;
    s = seg==0?s0: seg==1?s1: seg==2?s2: seg==3?s3: seg==4?s4: s5;
    dst = Wb; di = i;
  } else {
    unsigned j = i - 14155776u;                       // < 2359296
    s = (j < 1572864u) ? xh : xe;
    off = (j < 1572864u) ? j : j - 1572864u;
    dst = Xc; di = j;
  }
  f32x4 v = ((const f32x4*)s)[off];
  u16x4 o = { f2bf(v.x), f2bf(v.y), f2bf(v.z), f2bf(v.w) };
  ((u16x4*)dst)[di] = o;
}

// ---------------- 2-segment weight cast (wo/wao) ----------------
__global__ void k_castW2(const float* __restrict__ s0, const float* __restrict__ s1,
                         unsigned short* __restrict__ y){
  unsigned i = blockIdx.x*256 + threadIdx.x;          // < 2*2359296
  unsigned seg = i / 2359296u;
  unsigned off = i - seg*2359296u;
  const float* s = seg==0?s0:s1;
  f32x4 v = ((const f32x4*)s)[off];
  u16x4 o = { f2bf(v.x), f2bf(v.y), f2bf(v.z), f2bf(v.w) };
  ((u16x4*)y)[i] = o;
}

// ================= 256x256 8-wave QKV GEMM (BK=64, depth-1 dbuf) =================
// Round-17 proven (passed, ~180 us vs 308 for 128sq).
__global__ __launch_bounds__(512) void k_gemmP256(
    const unsigned short* __restrict__ X,
    const unsigned short* __restrict__ Wimg, const unsigned short* __restrict__ Wenc,
    const float* __restrict__ b0, const float* __restrict__ b1, const float* __restrict__ b2,
    const float* __restrict__ b3, const float* __restrict__ b4, const float* __restrict__ b5,
    unsigned short* __restrict__ Y, int rows_img)
{
  __shared__ unsigned short LDS[2][32768];   // per buf: A[256][64] @0, B[256][64] @16384 (elems)
  const int t = threadIdx.x, w = t>>6, l = t&63;
  const int li = l&15, g = l>>4;
  const int wr = w>>2, wc = w&3;             // 2 (M) x 4 (N) wave grid
  const int bxr = blockIdx.x, by = blockIdx.y;
  const int R = bxr*256;
  const int sec = by/12;                     // Q/K/V section
  const int Cn = (by%12)*256;                // col base within section
  const bool img = (R < rows_img);           // block-uniform
  const unsigned short* Wbase = (img ? Wimg : Wenc) + (long)sec*9437184 + (long)Cn*3072;
  const float* bias = img ? ((sec==0)?b0:(sec==1)?b1:b2)
                          : ((sec==0)?b3:(sec==1)?b4:b5);

  f32x4 acc[8][4] = {};

  auto stageC = [&](int buf, int kt, int c){
    int row = (c&3)*64 + (t>>3);
    int sgrp = (t&7) ^ (row&7);
    const unsigned short* src = (c<4)
        ? X + (long)(R+row)*3072 + kt*64 + sgrp*8
        : Wbase + (long)row*3072 + kt*64 + sgrp*8;
    gll16(src, &LDS[buf][(c<4?0:16384) + (c&3)*4096 + t*8]);
  };

  #pragma unroll
  for (int c=0;c<8;c++) stageC(0, 0, c);     // prologue: tile 0

  for (int kt=0; kt<48; kt++){
    __syncthreads();                         // tile kt resident; buf[(kt+1)&1] free
    const int buf = kt&1;
    const unsigned short* Ab = &LDS[buf][0];
    const unsigned short* Bb = &LDS[buf][16384];

    bf16x8 Bf[4][2];
    #pragma unroll
    for (int fc=0;fc<4;fc++)
      #pragma unroll
      for (int kh=0;kh<2;kh++){
        int brow = wc*64 + fc*16 + li;
        int bgrp = ((kh<<2) + g) ^ (brow&7);
        Bf[fc][kh] = *(const bf16x8*)&Bb[brow*64 + bgrp*8];
      }
    if (kt+1 < 48){
      #pragma unroll
      for (int c=0;c<4;c++) stageC(buf^1, kt+1, c);
    }

    #pragma unroll
    for (int p=0;p<4;p++){
      bf16x8 Af[2][2];
      #pragma unroll
      for (int f2=0;f2<2;f2++)
        #pragma unroll
        for (int kh=0;kh<2;kh++){
          int arow = wr*128 + (2*p+f2)*16 + li;
          int agrp = ((kh<<2) + g) ^ (arow&7);
          Af[f2][kh] = *(const bf16x8*)&Ab[arow*64 + agrp*8];
        }
      if (p==0 && kt+1 < 48){
        #pragma unroll
        for (int c=4;c<8;c++) stageC(buf^1, kt+1, c);
      }
      __builtin_amdgcn_s_setprio(1);
      #pragma unroll
      for (int f2=0;f2<2;f2++)
        #pragma unroll
        for (int fc=0;fc<4;fc++)
          #pragma unroll
          for (int kh=0;kh<2;kh++)
            acc[2*p+f2][fc] = __builtin_amdgcn_mfma_f32_16x16x32_bf16(
                                Af[f2][kh], Bf[fc][kh], acc[2*p+f2][fc], 0,0,0);
      __builtin_amdgcn_s_setprio(0);
    }
  }

  float bias_n[4];
  #pragma unroll
  for (int fc=0;fc<4;fc++) bias_n[fc] = bias[Cn + wc*64 + fc*16 + li];
  #pragma unroll
  for (int fr=0;fr<8;fr++){
    int row = R + wr*128 + fr*16 + g*4;
    #pragma unroll
    for (int fc=0;fc<4;fc++){
      long col = (long)by*256 + wc*64 + fc*16 + li;
      #pragma unroll
      for (int r=0;r<4;r++)
        Y[(long)(row+r)*9216 + col] = f2bf(acc[fr][fc][r] + bias_n[fc]);
    }
  }
}

// ---------------- merged RMSNorm + RoPE postprocess (4 segments, one launch) ----------------
// seg0: img Q (12288 blk) | seg1: img K (12288) | seg2: enc Q (6144) | seg3: enc K (6144)
// Bodies identical to round-5-proven k_ppqk; only param derivation moved in-kernel.
__global__ void k_ppqkAll(const unsigned short* __restrict__ Yb,
    const float* __restrict__ nq, const float* __restrict__ nk,
    const float* __restrict__ naq, const float* __restrict__ nak,
    const float* __restrict__ cs, const float* __restrict__ sn,
    unsigned short* __restrict__ Qb, unsigned short* __restrict__ Ki,
    unsigned short* __restrict__ Ke, float qsc)
{
  unsigned bb = blockIdx.x;
  int seg = bb>=30720u ? 3 : bb>=24576u ? 2 : bb>=12288u ? 1 : 0;
  unsigned local = bb - (seg==0?0u: seg==1?12288u: seg==2?24576u:30720u);
  const unsigned short* Y = Yb + (seg>=2 ? (long)2048*9216 : 0) + ((seg&1) ? 3072 : 0);
  const float* nw = seg==0?nq: seg==1?nk: seg==2?naq: nak;
  int T_log2  = seg<2 ? 11 : 10;
  int tpb_log2= seg<2 ? 10 : 9;
  int dest_off= seg==0 ? 512 : 0;
  int S       = (seg==0||seg==2) ? 1536 : (seg==1 ? 2048 : 512);
  int no_batch= (seg==1) ? 1 : 0;
  int pos_off = seg<2 ? 512 : 0;
  int pos_mask= seg<2 ? 1023 : 511;
  float qscale= (seg==0||seg==2) ? qsc : 1.0f;
  unsigned short* dst = (seg==0||seg==2) ? Qb : (seg==1 ? Ki : Ke);

  int rid = (int)local*4 + (threadIdx.x>>6);
  int l = threadIdx.x & 63;
  int h = rid >> T_log2, tk = rid & ((1<<T_log2)-1);
  unsigned pair = *(const unsigned*)(Y + (long)tk*9216 + h*128 + 2*l);
  float x0 = bf2f((unsigned short)(pair&0xffff));
  float x1 = bf2f((unsigned short)(pair>>16));
  float ss = x0*x0 + x1*x1;
  #pragma unroll
  for (int m=1;m<64;m<<=1) ss += __shfl_xor(ss, m);
  float rr = rsqrtf(ss*(1.0f/128.0f) + 1e-6f);
  x0 *= rr*nw[2*l]; x1 *= rr*nw[2*l+1];
  int p = pos_off + (tk & pos_mask);
  float c0 = cs[p*128 + 2*l], c1 = cs[p*128 + 2*l+1];
  float s0 = sn[p*128 + 2*l], s1 = sn[p*128 + 2*l+1];
  float o0 = (x0*c0 - x1*s0)*qscale;
  float o1 = (x1*c1 + x0*s1)*qscale;
  long idx;
  if (no_batch) idx = (long)h*S + tk;
  else {
    int b = tk >> tpb_log2;
    int sq = dest_off + (tk & ((1<<tpb_log2)-1));
    idx = (long)(b*24+h)*S + sq;
  }
  unsigned out = (unsigned)f2bf(o0) | ((unsigned)f2bf(o1)<<16);
  *(unsigned*)(dst + idx*128 + 2*l) = out;
}

// ---------------- merged V reorder + transpose (img | enc, one launch) ----------------
__global__ void k_ppvAll(const unsigned short* __restrict__ Yb,
                         unsigned short* __restrict__ Vi, unsigned short* __restrict__ Ve)
{
  __shared__ unsigned short tileS[64][136];
  int bx = blockIdx.x, h = blockIdx.y;
  bool img = bx < 32;                               // block-uniform
  const unsigned short* Y = Yb + (img ? 0 : (long)2048*9216) + 6144;
  unsigned short* Vt = img ? Vi : Ve;
  int vstr = img ? 2048 : 512;
  int no_batch = img ? 1 : 0;
  int tile0 = (img ? bx : bx-32)*64;

  int t = threadIdx.x;
  #pragma unroll
  for (int c=0;c<4;c++){
    int j = c*16 + (t>>4), col = (t&15)*8;
    *(u16x8*)&tileS[j][col] = *(const u16x8*)(Y + (long)(tile0+j)*9216 + h*128 + col);
  }
  __syncthreads();
  int d = t>>1, half = t&1;
  unsigned short tmp[32];
  #pragma unroll
  for (int i=0;i<32;i++) tmp[i] = tileS[half*32+i][d];
  long base;
  if (no_batch) base = ((long)h*128 + d)*vstr + tile0 + half*32;
  else { int b = tile0>>9; base = ((long)(b*24+h)*128 + d)*vstr + (tile0&511) + half*32; }
  #pragma unroll
  for (int k=0;k<4;k++) *(u16x8*)(Vt + base + k*8) = *(const u16x8*)&tmp[k*8];
}

// ---------------- fused-epilogue 128sq QKV GEMM (fallback path) ----------------
__global__ __launch_bounds__(256) void k_gemmP(
    const unsigned short* __restrict__ X,
    const unsigned short* __restrict__ Wimg, const unsigned short* __restrict__ Wenc,
    const float* __restrict__ b0, const float* __restrict__ b1, const float* __restrict__ b2,
    const float* __restrict__ b3, const float* __restrict__ b4, const float* __restrict__ b5,
    const float* __restrict__ nq_, const float* __restrict__ nk_,
    const float* __restrict__ naq_, const float* __restrict__ nak_,
    const float* __restrict__ cs, const float* __restrict__ sn,
    unsigned short* __restrict__ Qd,
    unsigned short* __restrict__ Kdi, unsigned short* __restrict__ Kde,
    unsigned short* __restrict__ Vdi, unsigned short* __restrict__ Vde,
    int rows_img)
{
  const int K = 3072;
  __shared__ unsigned short SH[16384];
  unsigned short (*As)[4096] = (unsigned short(*)[4096])SH;
  unsigned short (*Bs)[4096] = (unsigned short(*)[4096])(SH + 8192);
  const int t = threadIdx.x, w = t>>6, l = t&63;
  const int li = l&15, g = l>>4;
  const int by = blockIdx.y, bx = blockIdx.x;
  const int sec = by>=48 ? 2 : (by>=24 ? 1 : 0);
  const int hd = by - sec*24;
  const int Cl = hd*128;
  const int R = bx*128;
  const bool img = (R < rows_img);
  const unsigned short* Wp = (img ? Wimg : Wenc) + (long)sec*9437184 + (long)Cl*K;
  const float* bias = img ? ((sec==0)?b0:(sec==1)?b1:b2)
                          : ((sec==0)?b3:(sec==1)?b4:b5);
  const int wr = w>>1, wc = w&1;
  f32x4 acc[4][4] = {};

  auto stage = [&](int buf, int kt){
    const int k0 = kt*32;
    #pragma unroll
    for (int c=0;c<2;c++){
      int row = c*64 + (t>>2);
      int scol = ((t&3)<<3) ^ ((row&3)<<3) ^ (((row>>3)&1)<<4);
      gll16(X + (long)(R+row)*K + k0 + scol, &As[buf][c*2048 + w*512]);
      gll16(Wp + (long)row*K + k0 + scol, &Bs[buf][c*2048 + w*512]);
    }
  };

  stage(0,0);
  int buf = 0;
  for (int kt=0; kt<96; kt++){
    __syncthreads();
    if (kt+1 < 96) stage(buf^1, kt+1);
    bf16x8 a[4], b[4];
    #pragma unroll
    for (int m=0;m<4;m++){
      int ar = wr*64 + m*16 + li;
      int ac = (g<<3) ^ ((ar&3)<<3) ^ (((ar>>3)&1)<<4);
      a[m] = *(const bf16x8*)&As[buf][ar*32 + ac];
      int br = wc*64 + m*16 + li;
      int bc2 = (g<<3) ^ ((br&3)<<3) ^ (((br>>3)&1)<<4);
      b[m] = *(const bf16x8*)&Bs[buf][br*32 + bc2];
    }
    #pragma unroll
    for (int m=0;m<4;m++)
      #pragma unroll
      for (int n=0;n<4;n++)
        acc[m][n] = __builtin_amdgcn_mfma_f32_16x16x32_bf16(a[m], b[n], acc[m][n], 0,0,0);
    buf ^= 1;
  }

  float bias_n[4];
  #pragma unroll
  for (int n=0;n<4;n++) bias_n[n] = bias[Cl + wc*64 + n*16 + li];

  if (sec == 2){
    unsigned short* SHT = SH;
    unsigned short* Vd = img ? Vdi : Vde;
    #pragma unroll
    for (int pass=0; pass<2; pass++){
      __syncthreads();
      if (wc == pass){
        #pragma unroll
        for (int m=0;m<4;m++){
          int tok_l = wr*64 + m*16 + (g<<2);
          #pragma unroll
          for (int n=0;n<4;n++){
            int col_loc = n*16 + li;
            u16x4 v4 = { f2bf(acc[m][n][0]+bias_n[n]), f2bf(acc[m][n][1]+bias_n[n]),
                         f2bf(acc[m][n][2]+bias_n[n]), f2bf(acc[m][n][3]+bias_n[n]) };
            *(u16x4*)&SHT[col_loc*136 + tok_l] = v4;
          }
        }
      }
      __syncthreads();
      int d_loc = t>>2, qtr = t&3;
      int d = pass*64 + d_loc;
      int tok0 = R + qtr*32;
      long base;
      if (img) base = ((long)hd*128 + d)*2048 + tok0;
      else { int t2 = tok0 - rows_img; int b_ = t2>>9, s_ = t2&511;
             base = ((long)(b_*24+hd)*128 + d)*512 + s_; }
      #pragma unroll
      for (int k2=0;k2<4;k2++)
        *(u16x8*)(Vd + base + k2*8) = *(const u16x8*)&SHT[d_loc*136 + qtr*32 + k2*8];
    }
    return;
  }

  float part[4][4];
  #pragma unroll
  for (int m=0;m<4;m++)
    #pragma unroll
    for (int r=0;r<4;r++){
      float s_ = 0.f;
      #pragma unroll
      for (int n=0;n<4;n++){ float v = acc[m][n][r] + bias_n[n]; s_ += v*v; }
      part[m][r] = s_;
    }
  #pragma unroll
  for (int m=0;m<4;m++)
    #pragma unroll
    for (int r=0;r<4;r++){
      part[m][r] += __shfl_xor(part[m][r], 1);
      part[m][r] += __shfl_xor(part[m][r], 2);
      part[m][r] += __shfl_xor(part[m][r], 4);
      part[m][r] += __shfl_xor(part[m][r], 8);
    }
  __syncthreads();
  float* rs = (float*)SH;
  if (li == 0){
    #pragma unroll
    for (int m=0;m<4;m++)
      #pragma unroll
      for (int r=0;r<4;r++)
        rs[(wc*2+wr)*64 + m*16 + g*4 + r] = part[m][r];
  }
  __syncthreads();
  float fac[4][4];
  #pragma unroll
  for (int m=0;m<4;m++)
    #pragma unroll
    for (int r=0;r<4;r++){
      int idx = m*16 + g*4 + r;
      float tot = rs[(0*2+wr)*64 + idx] + rs[(1*2+wr)*64 + idx];
      fac[m][r] = rsqrtf(tot*(1.0f/128.0f) + 1e-6f);
    }

  const float* nw = (sec==0) ? (img ? nq_ : naq_) : (img ? nk_ : nak_);
  const float qs = (sec==0) ? (float)(0.08838834764831845 * 1.4426950408889634) : 1.0f;
  float nw_n[4];
  #pragma unroll
  for (int n=0;n<4;n++) nw_n[n] = nw[wc*64 + n*16 + li];

  unsigned short* Kd = img ? Kdi : Kde;

  #pragma unroll
  for (int m=0;m<4;m++){
    #pragma unroll
    for (int r=0;r<4;r++){
      int row_l = wr*64 + m*16 + g*4 + r;
      int t_row = R + row_l;
      int b_, s_, p_;
      if (img){ b_ = t_row>>10; s_ = t_row&1023; p_ = 512+s_; }
      else { int t2 = t_row - rows_img; b_ = t2>>9; s_ = t2&511; p_ = s_; }
      long didx;
      if (sec==0) didx = (long)(b_*24+hd)*1536 + (img ? 512+s_ : s_);
      else        didx = img ? ((long)hd*2048 + t_row) : ((long)(b_*24+hd)*512 + s_);
      const float* crow = cs + (long)p_*128;
      const float* srow = sn + (long)p_*128;
      unsigned short* drow = ((sec==0)?Qd:Kd) + didx*128;
      #pragma unroll
      for (int n=0;n<4;n++){
        int cl = wc*64 + n*16 + li;
        float x = (acc[m][n][r] + bias_n[n]) * fac[m][r] * nw_n[n];
        float xo = __shfl_xor(x, 1);
        float o_ = x*crow[cl] + ((l&1) ? xo*srow[cl] : -xo*srow[cl]);
        drow[cl] = f2bf(o_*qs);
      }
    }
  }
}

// ---------------- fused output GEMM (block-diagonal over rows) ----------------
__global__ __launch_bounds__(256) void k_gemmO(
    const unsigned short* __restrict__ X, const unsigned short* __restrict__ Wf,
    float* __restrict__ out, const float* __restrict__ bo, const float* __restrict__ bao)
{
  const int K = 3072;
  __shared__ unsigned short As[2][4096];
  __shared__ unsigned short Bs[2][4096];
  const int t = threadIdx.x, w = t>>6, l = t&63;
  unsigned wid = blockIdx.x + 24u*blockIdx.y;
  unsigned xc = wid & 7, ii = wid >> 3;
  unsigned xg = xc & 1, yg = xc >> 1;
  int bx = (int)(xg*12 + ii%12);
  int by = (int)(yg*6 + ii/12);
  const bool enc = bx >= 16;
  const unsigned short* Wp = Wf + (enc ? 9437184 : 0);
  const float* bias = enc ? bao : bo;
  const int R = bx*128, C = by*128;
  long xbase, obase;
  if (!enc){ xbase = (long)(R>>10)*1536 + 512 + (R&1023); obase = (long)R*3072; }
  else { int Rp = R-2048; xbase = (long)(Rp>>9)*1536 + (Rp&511); obase = 6291456 + (long)Rp*3072; }
  const int wr = w>>1, wc = w&1;
  f32x4 acc[4][4] = {};

  auto stage = [&](int buf, int kt){
    const int k0 = kt*32;
    #pragma unroll
    for (int c=0;c<2;c++){
      int row = c*64 + (t>>2);
      int scol = ((t&3)<<3) ^ ((row&3)<<3) ^ (((row>>3)&1)<<4);
      gll16(X + (xbase+row)*K + k0 + scol, &As[buf][c*2048 + w*512]);
      gll16(Wp + (long)(C+row)*K + k0 + scol, &Bs[buf][c*2048 + w*512]);
    }
  };

  stage(0,0);
  int buf = 0;
  for (int kt=0; kt<96; kt++){
    __syncthreads();
    if (kt+1 < 96) stage(buf^1, kt+1);
    bf16x8 a[4], b[4];
    #pragma unroll
    for (int m=0;m<4;m++){
      int ar = wr*64 + m*16 + (l&15);
      int ac = ((l>>4)<<3) ^ ((ar&3)<<3) ^ (((ar>>3)&1)<<4);
      a[m] = *(const bf16x8*)&As[buf][ar*32 + ac];
      int br = wc*64 + m*16 + (l&15);
      int bc2 = ((l>>4)<<3) ^ ((br&3)<<3) ^ (((br>>3)&1)<<4);
      b[m] = *(const bf16x8*)&Bs[buf][br*32 + bc2];
    }
    #pragma unroll
    for (int m=0;m<4;m++)
      #pragma unroll
      for (int n=0;n<4;n++)
        acc[m][n] = __builtin_amdgcn_mfma_f32_16x16x32_bf16(a[m], b[n], acc[m][n], 0,0,0);
    buf ^= 1;
  }

  #pragma unroll
  for (int m=0;m<4;m++){
    int rl = wr*64 + m*16 + ((l>>4)<<2);
    #pragma unroll
    for (int n=0;n<4;n++){
      int col = C + wc*64 + n*16 + (l&15);
      float bvv = bias[col];
      #pragma unroll
      for (int r=0;r<4;r++)
        out[obase + (long)(rl+r)*3072 + col] = acc[m][n][r] + bvv;
    }
  }
}

// ---------------- flash attention (round-17 proven) ----------------
__global__ __launch_bounds__(256) void k_attn(
    const unsigned short* __restrict__ Q,
    const unsigned short* __restrict__ Ke, const unsigned short* __restrict__ Ki,
    const unsigned short* __restrict__ Ve, const unsigned short* __restrict__ Vi,
    unsigned short* __restrict__ AO)
{
  __shared__ unsigned short Ks[8192];
  __shared__ unsigned short Vs[8192];
  __shared__ unsigned short Ps[4][1408];
  const int t = threadIdx.x, w = t>>6, l = t&63;
  unsigned wid = blockIdx.x + 24u*blockIdx.y + 576u*blockIdx.z;
  unsigned xc = wid & 7, ii = wid >> 3;
  int h = (int)(xc*3 + ii/48);
  unsigned rem = ii % 48;
  int b = (int)(rem/24);
  int qx = (int)(rem%24);
  const int bh = b*24 + h;
  const int q0 = qx*64 + w*16;
  const int g = l>>4;

  auto stageK = [&](int jt){
    const unsigned short* ksrc = (jt < 8) ? Ke + ((long)bh*512 + jt*64)*128
                                          : Ki + ((long)h*2048 + (jt-8)*64)*128;
    #pragma unroll
    for (int c=0;c<4;c++){
      int row = c*16 + (t>>4);
      int col = ((t&15)<<3) ^ ((row&7)<<3);
      gll16(ksrc + row*128 + col, &Ks[c*2048 + w*512]);
    }
  };
  auto stageV = [&](int jt){
    const unsigned short* vsrc; long vstr;
    if (jt < 8){ vsrc = Ve + (long)bh*65536 + jt*64; vstr = 512; }
    else { vsrc = Vi + (long)h*262144 + (jt-8)*64; vstr = 2048; }
    #pragma unroll
    for (int c=0;c<4;c++){
      int row = c*32 + (t>>3);
      int col = ((t&7)<<3) ^ ((row&7)<<3);
      gll16(vsrc + (long)row*vstr + col, &Vs[c*2048 + w*512]);
    }
  };

  bf16x8 qf[4];
  {
    const unsigned short* qp = Q + ((long)bh*1536 + q0 + (l&15))*128 + (g<<3);
    #pragma unroll
    for (int kc=0;kc<4;kc++) qf[kc] = *(const bf16x8*)(qp + kc*32);
  }
  f32x4 o[8] = {};
  float mx = -1e30f;
  float ls = 0.f;

  stageK(0);
  for (int jt=0; jt<40; jt++){
    __syncthreads();
    stageV(jt);

    f32x4 sf[4];
    __builtin_amdgcn_s_setprio(1);
    #pragma unroll
    for (int ct=0;ct<4;ct++){
      f32x4 s = {};
      #pragma unroll
      for (int kc=0;kc<4;kc++){
        int krow = ct*16 + (l&15);
        int kcol = (kc*32 + (g<<3)) ^ ((krow&7)<<3);
        bf16x8 kb = *(const bf16x8*)&Ks[krow*128 + kcol];
        s = __builtin_amdgcn_mfma_f32_16x16x32_bf16(kb, qf[kc], s, 0,0,0);
      }
      sf[ct] = s;
    }
    __builtin_amdgcn_s_setprio(0);

    float pm = sf[0][0];
    #pragma unroll
    for (int ct=0;ct<4;ct++)
      #pragma unroll
      for (int r=0;r<4;r++) pm = fmaxf(pm, sf[ct][r]);
    if (!__all(pm <= mx + 8.0f)){
      float tmax = pm;
      tmax = fmaxf(tmax, __shfl_xor(tmax, 16));
      tmax = fmaxf(tmax, __shfl_xor(tmax, 32));
      float mn = fmaxf(mx, tmax);
      float al = exp2f(mx - mn);
      mx = mn;
      ls *= al;
      #pragma unroll
      for (int r=0;r<4;r++){
        float alo = __shfl(al, (l&48) | ((g<<2)+r));
        #pragma unroll
        for (int f=0;f<8;f++) o[f][r] *= alo;
      }
    }
    #pragma unroll
    for (int ct=0;ct<4;ct++){
      float p0 = exp2f(sf[ct][0]-mx), p1 = exp2f(sf[ct][1]-mx);
      float p2 = exp2f(sf[ct][2]-mx), p3 = exp2f(sf[ct][3]-mx);
      ls += (p0+p1)+(p2+p3);
      uint2v pk = { cvtpk(p0,p1), cvtpk(p2,p3) };
      *(uint2v*)&Ps[w][(l&15)*88 + ct*16 + (g<<2)] = pk;
    }
    __syncthreads();

    if (jt+1 < 40) stageK(jt+1);

    bf16x8 pa[2];
    #pragma unroll
    for (int kc=0;kc<2;kc++)
      pa[kc] = *(const bf16x8*)&Ps[w][(l&15)*88 + kc*32 + (g<<3)];
    __builtin_amdgcn_s_setprio(1);
    #pragma unroll
    for (int f=0;f<8;f++){
      #pragma unroll
      for (int kc=0;kc<2;kc++){
        int vrow = f*16 + (l&15);
        int vcol = (kc*32 + (g<<3)) ^ ((vrow&7)<<3);
        bf16x8 vb = *(const bf16x8*)&Vs[vrow*64 + vcol];
        o[f] = __builtin_amdgcn_mfma_f32_16x16x32_bf16(pa[kc], vb, o[f], 0,0,0);
      }
    }
    __builtin_amdgcn_s_setprio(0);
  }

  ls += __shfl_xor(ls, 16);
  ls += __shfl_xor(ls, 32);
  #pragma unroll
  for (int r=0;r<4;r++){
    float lso = __shfl(ls, (l&48) | ((g<<2)+r));
    float inv = 1.0f/lso;
    int qrow = q0 + (g<<2) + r;
    #pragma unroll
    for (int f=0;f<8;f++){
      AO[((long)b*1536 + qrow)*3072 + h*128 + f*16 + (l&15)] = f2bf(o[f][r]*inv);
    }
  }
}

// ---------------- host launch ----------------
extern "C" void kernel_launch(void* const* d_in, const int* in_sizes, int n_in,
                              void* d_out, int out_size, void* d_ws, size_t ws_size,
                              hipStream_t stream)
{
  const float* hs  = (const float*)d_in[0];
  const float* ehs = (const float*)d_in[1];
  const float* rc  = (const float*)d_in[2];
  const float* rs_ = (const float*)d_in[3];
  const float* wq = (const float*)d_in[4];  const float* bq = (const float*)d_in[5];
  const float* wk = (const float*)d_in[6];  const float* bk = (const float*)d_in[7];
  const float* wv = (const float*)d_in[8];  const float* bv = (const float*)d_in[9];
  const float* waq= (const float*)d_in[10]; const float* baq= (const float*)d_in[11];
  const float* wak= (const float*)d_in[12]; const float* bak= (const float*)d_in[13];
  const float* wav= (const float*)d_in[14]; const float* bav= (const float*)d_in[15];
  const float* wo = (const float*)d_in[16]; const float* bo = (const float*)d_in[17];
  const float* wao= (const float*)d_in[18]; const float* bao= (const float*)d_in[19];
  const float* nq = (const float*)d_in[20]; const float* nk = (const float*)d_in[21];
  const float* naq= (const float*)d_in[22]; const float* nak= (const float*)d_in[23];

  const float qsc = (float)(0.08838834764831845 * 1.4426950408889634);

  char* p = (char*)d_ws;
  auto alloc = [&](size_t bytes){ char* r = p; p += bytes; return r; };

  if (ws_size >= (size_t)245366784){
    // ---------- main path (245.4 MB) ----------
    unsigned short* Xh = (unsigned short*)alloc(12582912);  // [2048][3072]
    unsigned short* Xe = (unsigned short*)alloc(6291456);   // [1024][3072] (contiguous)
    unsigned short* Wb = (unsigned short*)alloc(113246208); // 6 QKV weight slots bf16
    unsigned short* Yb = (unsigned short*)alloc(56623104);  // [3072][9216]
    unsigned short* Qb = (unsigned short*)alloc(18874368);  // Q [2][24][1536][128]
    unsigned short* Ke = (unsigned short*)alloc(6291456);   // Kenc
    unsigned short* Ki = (unsigned short*)alloc(12582912);  // Kimg
    unsigned short* Ve = (unsigned short*)alloc(6291456);   // Vtenc
    unsigned short* Vi = (unsigned short*)alloc(12582912);  // Vtimg
    unsigned short* AO = Xh;                                // aliases Xh+Xe (dead by attn)
    (void)Xe;

    k_castA6X<<<64512,256,0,stream>>>(wq, wk, wv, waq, wak, wav, hs, ehs, Wb, Xh);

    k_gemmP256<<<dim3(12,36),512,0,stream>>>(Xh, Wb, Wb + (long)3*9437184,
                                             bq, bk, bv, baq, bak, bav, Yb, 2048);

    k_ppqkAll<<<36864,256,0,stream>>>(Yb, nq, nk, naq, nak, rc, rs_, Qb, Ki, Ke, qsc);
    k_ppvAll<<<dim3(48,24),256,0,stream>>>(Yb, Vi, Ve);

    k_attn<<<dim3(24,24,2),256,0,stream>>>(Qb, Ke, Ki, Ve, Vi, AO);

    k_castW2<<<18432,256,0,stream>>>(wo, wao, Wb);          // QKV weights dead
    k_gemmO<<<dim3(24,24),256,0,stream>>>(AO, Wb, (float*)d_out, bo, bao);
  } else {
    // ---------- fallback path (132.1 MB): fused-epilogue 128sq pipeline ----------
    unsigned short* Xh = (unsigned short*)alloc(12582912);
    unsigned short* Xe = (unsigned short*)alloc(6291456);
    unsigned short* Wb = (unsigned short*)alloc(56623104);  // 3 slots
    unsigned short* Qb = (unsigned short*)alloc(18874368);
    unsigned short* Ke = (unsigned short*)alloc(6291456);
    unsigned short* Ki = (unsigned short*)alloc(12582912);
    unsigned short* Ve = (unsigned short*)alloc(6291456);
    unsigned short* Vi = (unsigned short*)alloc(12582912);
    unsigned short* AO = Xh;

    k_castX2<<<9216,256,0,stream>>>(hs, ehs, Xh);

    k_cast<<<9216,256,0,stream>>>(wq, Wb, 2359296);
    k_cast<<<9216,256,0,stream>>>(wk, Wb + 9437184, 2359296);
    k_cast<<<9216,256,0,stream>>>(wv, Wb + 18874368, 2359296);
    k_gemmP<<<dim3(16,72),256,0,stream>>>(Xh, Wb, Wb,
                                          bq, bk, bv, bq, bk, bv,
                                          nq, nk, nq, nk, rc, rs_,
                                          Qb, Ki, Ke, Vi, Ve, 1<<28);

    k_cast<<<9216,256,0,stream>>>(waq, Wb, 2359296);
    k_cast<<<9216,256,0,stream>>>(wak, Wb + 9437184, 2359296);
    k_cast<<<9216,256,0,stream>>>(wav, Wb + 18874368, 2359296);
    k_gemmP<<<dim3(8,72),256,0,stream>>>(Xe, Wb, Wb,
                                         baq, bak, bav, baq, bak, bav,
                                         naq, nak, naq, nak, rc, rs_,
                                         Qb, Ki, Ke, Vi, Ve, 0);

    k_attn<<<dim3(24,24,2),256,0,stream>>>(Qb, Ke, Ki, Ve, Vi, AO);

    k_castW2<<<18432,256,0,stream>>>(wo, wao, Wb);
    k_gemmO<<<dim3(24,24),256,0,stream>>>(AO, Wb, (float*)d_out, bo, bao);
  }
}